// Round 15
// baseline (601.043 us; speedup 1.0000x reference)
//
#include <hip/hip_runtime.h>
#include <hip/hip_bf16.h>

// ---------------------------------------------------------------------------
// UNet3D dense forward, round 15: R14 + full consumer-BN fusion.
//  - s1/s2 in-place bn_relu passes removed; BN+ReLU applied at every consumer
//    load (V2 B-loads, V0/tconv staging for both concat inputs).
//  - per-layer persistent scale/shift buffers (s1, s2 now live to the end).
//  - 17 dispatches total.
// ---------------------------------------------------------------------------

using bf16 = __hip_bfloat16;
using ushort4v = __attribute__((ext_vector_type(4))) unsigned short;
using ushort8  = __attribute__((ext_vector_type(8))) unsigned short;
using short8   = __attribute__((ext_vector_type(8))) short;
using f32x4    = __attribute__((ext_vector_type(4))) float;
using float4v  = __attribute__((ext_vector_type(4))) float;

#define TPB 256

static inline int cdiv_l(long a, int b){ return (int)((a + b - 1) / b); }

__device__ __forceinline__ float b2f(unsigned short u){
  union { unsigned int i; float f; } v; v.i = ((unsigned int)u) << 16; return v.f;
}
__device__ __forceinline__ unsigned short f2b(float f){
  union { bf16 h; unsigned short u; } v; v.h = __float2bfloat16(f); return v.u;
}
__device__ __forceinline__ short8 asS8(ushort8 u){
  union { ushort8 a; short8 b; } x; x.a = u; return x.b;
}
__device__ __forceinline__ ushort8 bnApply8(ushort8 v, const float* sc, const float* sh, int c){
  float4v s0 = *(const float4v*)(sc + c), s1v = *(const float4v*)(sc + c + 4);
  float4v h0 = *(const float4v*)(sh + c), h1v = *(const float4v*)(sh + c + 4);
  ushort8 r;
#pragma unroll
  for (int j = 0; j < 4; ++j){ float y = b2f(v[j]) * s0[j] + h0[j]; r[j] = f2b(y > 0.f ? y : 0.f); }
#pragma unroll
  for (int j = 0; j < 4; ++j){ float y = b2f(v[j+4]) * s1v[j] + h1v[j]; r[j+4] = f2b(y > 0.f ? y : 0.f); }
  return r;
}

// ---------------- merged weight repack ----------------
__global__ void rp_all(const float* __restrict__ w0, const float* __restrict__ w1,
                       const float* __restrict__ w2, const float* __restrict__ wt2r,
                       const float* __restrict__ wt2c, const float* __restrict__ wt1r,
                       const float* __restrict__ wt1c, const float* __restrict__ wt0r,
                       const float* __restrict__ wt0c,
                       unsigned short* __restrict__ wb0p, unsigned short* __restrict__ wb1,
                       unsigned short* __restrict__ wb2, unsigned short* __restrict__ wb2r,
                       unsigned short* __restrict__ wb2c, unsigned short* __restrict__ wb1r,
                       unsigned short* __restrict__ wb1c, unsigned short* __restrict__ wbrec,
                       unsigned short* __restrict__ wbcl){
  int idx = blockIdx.x * TPB + threadIdx.x;
  auto enc = [](const float* w, unsigned short* d, int i, int Cin, int Cout){
    int ci = i % Cin; int t = i / Cin; int co = t % Cout; int tap = t / Cout;
    d[i] = f2b(w[((long)co * Cin + ci) * 27 + tap]);
  };
  auto dec = [](const float* w, unsigned short* d, int i, int Cin, int Cout, int CIP, int COP){
    int ci = i % CIP; int t = i / CIP; int co = t % COP; int tap = t / COP;
    float v = (ci < Cin && co < Cout) ? w[((long)tap * Cin + ci) * Cout + co] : 0.f;
    d[i] = f2b(v);
  };
  if (idx < 14336) {
    int i = idx;
    int k = i & 31; int t = i >> 5; int co = t & 31; int pp = t >> 5;
    int tap = pp * 2 + (k >> 4); int ci = k & 15;
    float v = (tap < 27) ? w0[((long)co * 16 + ci) * 27 + tap] : 0.f;
    wb0p[i] = f2b(v);
  }
  else if (idx <   69632) enc(w1,  wb1,  idx - 14336,  32, 64);
  else if (idx <  290816) enc(w2,  wb2,  idx - 69632,  64, 128);
  else if (idx <  512000) dec(wt2r, wb2r, idx - 290816, 128, 64, 128, 64);
  else if (idx <  733184) dec(wt2c, wb2c, idx - 512000, 128, 64, 128, 64);
  else if (idx <  788480) dec(wt1r, wb1r, idx - 733184,  64, 32,  64, 32);
  else if (idx < 1009664) dec(wt1c, wb1c, idx - 788480, 128, 64, 128, 64);
  else if (idx < 1023488) dec(wt0r, wbrec, idx - 1009664, 32, 16,  32, 16);
  else if (idx < 1064960) dec(wt0c, wbcl, idx - 1023488, 96,  2,  96, 16);
}

// ---------------- x transpose: NCDHW fp32 -> NDHWC bf16 (C=16) ----------------
__global__ void xpose_k(const float* __restrict__ x, unsigned short* __restrict__ xt){
  __shared__ float l[16][257];
  int t = threadIdx.x;
  long p0 = (long)blockIdx.x * 256;
  int n = (int)(p0 >> 18);
  long off = p0 & 262143;
  const float* xb = x + ((long)n * 16) * 262144 + off;
#pragma unroll
  for (int c = 0; c < 16; ++c) l[c][t] = xb[(long)c * 262144 + t];
  __syncthreads();
  ushort8 u0, u1;
#pragma unroll
  for (int k = 0; k < 8; ++k){ u0[k] = f2b(l[k][t]); u1[k] = f2b(l[k + 8][t]); }
  unsigned short* o = xt + (p0 + t) * 16;
  *(ushort8*)o = u0; *(ushort8*)(o + 8) = u1;
}

// ---------------- quadrant stride-2 tconv, dbuf LDS, BN on both inputs -----
template <int CO_TILES, bool STATS>
__global__ __launch_bounds__(TPB, 2) void tconv_quad(
    const unsigned short* __restrict__ inA, int CA,
    const unsigned short* __restrict__ inB, int CB,
    const float* __restrict__ scA, const float* __restrict__ shA,
    const float* __restrict__ scB, const float* __restrict__ shB,
    const unsigned short* __restrict__ wb,
    unsigned short* __restrict__ out,
    float* __restrict__ part2, int NB,
    int N, int Cout, int COP, int CIP, int G) {
  __shared__ unsigned short xs[2][4 * 432 * 8];
  const int tid = threadIdx.x, wv = tid >> 6, l = tid & 63, l15 = l & 15, lg = l >> 4;
  int ntW = G >> 4, ntH = G >> 2, ntD = G >> 2;
  int bx = blockIdx.x;
  const int blkLin = blockIdx.x * 4 + blockIdx.z;
  int w0 = (bx % ntW) << 4; bx /= ntW;
  int h0 = (bx % ntH) << 2; bx /= ntH;
  int d0 = (bx % ntD) << 2; int n = bx / ntD;
  const int co0 = blockIdx.y * (16 * CO_TILES);
  const int quad = blockIdx.z;
  const int pd = (quad >> 1) & 1, ph = quad & 1;
  const long spin = (long)G * G * G;

  int nkd, kd_[2], dd_[2], nkh, kh_[2], dh_[2];
  if (pd){ nkd=1; kd_[0]=1; dd_[0]=0; } else { nkd=2; kd_[0]=0; dd_[0]=-1; kd_[1]=2; dd_[1]=0; }
  if (ph){ nkh=1; kh_[0]=1; dh_[0]=0; } else { nkh=2; kh_[0]=0; dh_[0]=-1; kh_[1]=2; dh_[1]=0; }

  f32x4 acc[CO_TILES][4][2];
#pragma unroll
  for (int ct = 0; ct < CO_TILES; ++ct)
#pragma unroll
    for (int j = 0; j < 4; ++j)
#pragma unroll
      for (int p = 0; p < 2; ++p) acc[ct][j][p] = (f32x4){0.f, 0.f, 0.f, 0.f};

  auto stage = [&](int ch, int buf) {
    int c0 = ch << 5;
    const unsigned short* src; int Cs, cl_;
    const float* scU; const float* shU;
    if (c0 < CA){ src = inA; Cs = CA; cl_ = c0; scU = scA; shU = shA; }
    else        { src = inB; Cs = CB; cl_ = c0 - CA; scU = scB; shU = shB; }
    const unsigned short* sb = src + (long)n * Cs * spin;
    unsigned short* xb = &xs[buf][0];
    for (int idx = tid; idx < 4 * 425; idx += TPB) {
      int q = idx / 425, pt = idx - q * 425;
      int zw = pt % 17; int zt = pt / 17; int zh = zt % 5; int zd = zt / 5;
      int gd = d0 + zd - 1, gh = h0 + zh - 1, gw = w0 + zw - 1;
      ushort8 v = (ushort8){0,0,0,0,0,0,0,0};
      if ((unsigned)gd < (unsigned)G && (unsigned)gh < (unsigned)G && (unsigned)gw < (unsigned)G) {
        v = *(const ushort8*)(sb + (((long)gd * G + gh) * G + gw) * Cs + cl_ + q * 8);
        if (scU) v = bnApply8(v, scU, shU, cl_ + q * 8);
      }
      *(ushort8*)(xb + (q * 432 + pt) * 8) = v;
    }
  };

  const int nch = CIP >> 5;
  stage(0, 0);
  __syncthreads();
#pragma unroll 1
  for (int ch = 0; ch < nch; ++ch) {
    int cur = ch & 1;
    int c0 = ch << 5;
    if (ch + 1 < nch) stage(ch + 1, cur ^ 1);
    const unsigned short* xr = &xs[cur][0];
#pragma unroll 1
    for (int a = 0; a < nkd; ++a) {
      int zd = wv + 1 + dd_[a];
#pragma unroll 1
      for (int b = 0; b < nkh; ++b) {
        int tapb = (kd_[a] * 3 + kh_[b]) * 3;
        const unsigned short* ap = wb + ((long)tapb * COP + co0 + l15) * CIP + c0 + lg * 8;
        long tstride = (long)COP * CIP;
        short8 Ak0[CO_TILES], Ak1[CO_TILES], Ak2[CO_TILES];
#pragma unroll
        for (int ct = 0; ct < CO_TILES; ++ct) {
          Ak0[ct] = *(const short8*)(ap + ct * 16 * CIP);
          Ak1[ct] = *(const short8*)(ap + tstride + ct * 16 * CIP);
          Ak2[ct] = *(const short8*)(ap + 2 * tstride + ct * 16 * CIP);
        }
        int zh0 = 1 + dh_[b];
#pragma unroll
        for (int j = 0; j < 4; ++j) {
          int basept = (zd * 5 + (j + zh0)) * 17 + l15;
          short8 Bm = *(const short8*)(xr + (lg * 432 + basept) * 8);
          short8 B0 = *(const short8*)(xr + (lg * 432 + basept + 1) * 8);
#pragma unroll
          for (int ct = 0; ct < CO_TILES; ++ct) {
            acc[ct][j][0] = __builtin_amdgcn_mfma_f32_16x16x32_bf16(Ak0[ct], Bm, acc[ct][j][0], 0, 0, 0);
            acc[ct][j][0] = __builtin_amdgcn_mfma_f32_16x16x32_bf16(Ak2[ct], B0, acc[ct][j][0], 0, 0, 0);
            acc[ct][j][1] = __builtin_amdgcn_mfma_f32_16x16x32_bf16(Ak1[ct], B0, acc[ct][j][1], 0, 0, 0);
          }
        }
      }
    }
    __syncthreads();
  }

  // ---- dense store ----
  int Gout = 2 * G; long spo = (long)Gout * Gout * Gout;
  int od = 2 * (d0 + wv) + pd;
#pragma unroll
  for (int j = 0; j < 4; ++j) {
    int oh = 2 * (h0 + j) + ph;
#pragma unroll
    for (int p = 0; p < 2; ++p) {
      int ow = 2 * (w0 + l15) + p;
      long pt = ((long)od * Gout + oh) * Gout + ow;
#pragma unroll
      for (int ct = 0; ct < CO_TILES; ++ct) {
        ushort4v pk;
#pragma unroll
        for (int r = 0; r < 4; ++r) pk[r] = f2b(acc[ct][j][p][r]);
        *(ushort4v*)(out + ((long)n * spo + pt) * Cout + co0 + ct * 16 + lg * 4) = pk;
      }
    }
  }

  if constexpr (STATS) {
    __shared__ float redS[4][CO_TILES][4][4];
    __shared__ float redQ[4][CO_TILES][4][4];
#pragma unroll
    for (int ct = 0; ct < CO_TILES; ++ct)
#pragma unroll
      for (int r = 0; r < 4; ++r) {
        float s = 0.f, q = 0.f;
#pragma unroll
        for (int j = 0; j < 4; ++j)
#pragma unroll
          for (int p = 0; p < 2; ++p) { float a = acc[ct][j][p][r]; s += a; q += a * a; }
#pragma unroll
        for (int m = 1; m < 16; m <<= 1) { s += __shfl_xor(s, m); q += __shfl_xor(q, m); }
        if (l15 == 0) { redS[wv][ct][lg][r] = s; redQ[wv][ct][lg][r] = q; }
      }
    __syncthreads();
    if (tid < CO_TILES * 16) {
      int ct = tid >> 4, lg2 = (tid >> 2) & 3, r = tid & 3;
      float s = 0.f, q = 0.f;
#pragma unroll
      for (int w2 = 0; w2 < 4; ++w2) { s += redS[w2][ct][lg2][r]; q += redQ[w2][ct][lg2][r]; }
      int c = co0 + ct * 16 + lg2 * 4 + r;
      long slot = (long)c * NB + blkLin;
      part2[slot * 2] = s; part2[slot * 2 + 1] = q;
    }
  }
}

// ---------------- dual-head quadrant tconv2 (shared s4 staging) ------------
__global__ __launch_bounds__(TPB) void tconv_dual(
    const unsigned short* __restrict__ in, int CI,
    const float* __restrict__ scA, const float* __restrict__ shA,
    const unsigned short* __restrict__ wbA, const unsigned short* __restrict__ wbB,
    unsigned short* __restrict__ outA, unsigned short* __restrict__ outB,
    float* __restrict__ p2A, float* __restrict__ p2B, int NB,
    int N, int Cout, int COP, int CIP, int G) {
  const int CT = 2;
  __shared__ unsigned short xs[4 * 432 * 8];
  const int tid = threadIdx.x, wv = tid >> 6, l = tid & 63, l15 = l & 15, lg = l >> 4;
  int ntW = G >> 4, ntH = G >> 2, ntD = G >> 2;
  int bx = blockIdx.x;
  const int blkLin = blockIdx.x * 4 + blockIdx.z;
  int w0 = (bx % ntW) << 4; bx /= ntW;
  int h0 = (bx % ntH) << 2; bx /= ntH;
  int d0 = (bx % ntD) << 2; int n = bx / ntD;
  const int co0 = blockIdx.y * (16 * CT);
  const int quad = blockIdx.z;
  const int pd = (quad >> 1) & 1, ph = quad & 1;
  const long spin = (long)G * G * G;

  int nkd, kd_[2], dd_[2], nkh, kh_[2], dh_[2];
  if (pd){ nkd=1; kd_[0]=1; dd_[0]=0; } else { nkd=2; kd_[0]=0; dd_[0]=-1; kd_[1]=2; dd_[1]=0; }
  if (ph){ nkh=1; kh_[0]=1; dh_[0]=0; } else { nkh=2; kh_[0]=0; dh_[0]=-1; kh_[1]=2; dh_[1]=0; }

  f32x4 acc[2][CT][4][2];
#pragma unroll
  for (int h = 0; h < 2; ++h)
#pragma unroll
    for (int ct = 0; ct < CT; ++ct)
#pragma unroll
      for (int j = 0; j < 4; ++j)
#pragma unroll
        for (int p = 0; p < 2; ++p) acc[h][ct][j][p] = (f32x4){0.f, 0.f, 0.f, 0.f};

  const int nch = CIP >> 5;
#pragma unroll 1
  for (int ch = 0; ch < nch; ++ch) {
    int c0 = ch << 5;
    const unsigned short* sb = in + (long)n * CI * spin;
    __syncthreads();
    for (int idx = tid; idx < 4 * 425; idx += TPB) {
      int q = idx / 425, pt = idx - q * 425;
      int zw = pt % 17; int zt = pt / 17; int zh = zt % 5; int zd = zt / 5;
      int gd = d0 + zd - 1, gh = h0 + zh - 1, gw = w0 + zw - 1;
      ushort8 v = (ushort8){0,0,0,0,0,0,0,0};
      if ((unsigned)gd < (unsigned)G && (unsigned)gh < (unsigned)G && (unsigned)gw < (unsigned)G) {
        v = *(const ushort8*)(sb + (((long)gd * G + gh) * G + gw) * CI + c0 + q * 8);
        v = bnApply8(v, scA, shA, c0 + q * 8);
      }
      *(ushort8*)(xs + (q * 432 + pt) * 8) = v;
    }
    __syncthreads();
#pragma unroll 1
    for (int a = 0; a < nkd; ++a) {
      int zd = wv + 1 + dd_[a];
#pragma unroll 1
      for (int b = 0; b < nkh; ++b) {
        int tapb = (kd_[a] * 3 + kh_[b]) * 3;
        long tstride = (long)COP * CIP;
        long abase = ((long)tapb * COP + co0 + l15) * CIP + c0 + lg * 8;
        int zh0 = 1 + dh_[b];
#pragma unroll
        for (int h = 0; h < 2; ++h) {
          const unsigned short* ap = (h == 0 ? wbA : wbB) + abase;
          short8 Ak0[CT], Ak1[CT], Ak2[CT];
#pragma unroll
          for (int ct = 0; ct < CT; ++ct) {
            Ak0[ct] = *(const short8*)(ap + ct * 16 * CIP);
            Ak1[ct] = *(const short8*)(ap + tstride + ct * 16 * CIP);
            Ak2[ct] = *(const short8*)(ap + 2 * tstride + ct * 16 * CIP);
          }
#pragma unroll
          for (int j = 0; j < 4; ++j) {
            int basept = (zd * 5 + (j + zh0)) * 17 + l15;
            short8 Bm = *(const short8*)(xs + (lg * 432 + basept) * 8);
            short8 B0 = *(const short8*)(xs + (lg * 432 + basept + 1) * 8);
#pragma unroll
            for (int ct = 0; ct < CT; ++ct) {
              acc[h][ct][j][0] = __builtin_amdgcn_mfma_f32_16x16x32_bf16(Ak0[ct], Bm, acc[h][ct][j][0], 0, 0, 0);
              acc[h][ct][j][0] = __builtin_amdgcn_mfma_f32_16x16x32_bf16(Ak2[ct], B0, acc[h][ct][j][0], 0, 0, 0);
              acc[h][ct][j][1] = __builtin_amdgcn_mfma_f32_16x16x32_bf16(Ak1[ct], B0, acc[h][ct][j][1], 0, 0, 0);
            }
          }
        }
      }
    }
  }

  // ---- dense store (both heads) ----
  int Gout = 2 * G; long spo = (long)Gout * Gout * Gout;
  int od = 2 * (d0 + wv) + pd;
#pragma unroll
  for (int j = 0; j < 4; ++j) {
    int oh = 2 * (h0 + j) + ph;
#pragma unroll
    for (int p = 0; p < 2; ++p) {
      int ow = 2 * (w0 + l15) + p;
      long pt = ((long)od * Gout + oh) * Gout + ow;
#pragma unroll
      for (int h = 0; h < 2; ++h) {
        unsigned short* o = h == 0 ? outA : outB;
#pragma unroll
        for (int ct = 0; ct < CT; ++ct) {
          ushort4v pk;
#pragma unroll
          for (int r = 0; r < 4; ++r) pk[r] = f2b(acc[h][ct][j][p][r]);
          *(ushort4v*)(o + ((long)n * spo + pt) * Cout + co0 + ct * 16 + lg * 4) = pk;
        }
      }
    }
  }

  // ---- stats, two rounds ----
  __shared__ float redS[4][CT][4][4];
  __shared__ float redQ[4][CT][4][4];
#pragma unroll 1
  for (int h = 0; h < 2; ++h) {
    __syncthreads();
#pragma unroll
    for (int ct = 0; ct < CT; ++ct)
#pragma unroll
      for (int r = 0; r < 4; ++r) {
        float s = 0.f, q = 0.f;
#pragma unroll
        for (int j = 0; j < 4; ++j)
#pragma unroll
          for (int p = 0; p < 2; ++p) { float a = acc[h][ct][j][p][r]; s += a; q += a * a; }
#pragma unroll
        for (int m = 1; m < 16; m <<= 1) { s += __shfl_xor(s, m); q += __shfl_xor(q, m); }
        if (l15 == 0) { redS[wv][ct][lg][r] = s; redQ[wv][ct][lg][r] = q; }
      }
    __syncthreads();
    if (tid < CT * 16) {
      int ct = tid >> 4, lg2 = (tid >> 2) & 3, r = tid & 3;
      float s = 0.f, q = 0.f;
#pragma unroll
      for (int w2 = 0; w2 < 4; ++w2) { s += redS[w2][ct][lg2][r]; q += redQ[w2][ct][lg2][r]; }
      int c = co0 + ct * 16 + lg2 * 4 + r;
      long slot = (long)c * NB + blkLin;
      float* p2 = h == 0 ? p2A : p2B;
      p2[slot * 2] = s; p2[slot * 2 + 1] = q;
    }
  }
}

// ---------------- unified NDHWC MFMA conv ----------------
// VARIANT 0 / PAIRED: stride-1 conv, LDS-staged, 2d x 8h x 16w, BN both inputs.
// VARIANT 2: stride-2 conv, direct-global B with fused BN, 4d x 4h x 16w.
template <int VARIANT, int CO_TILES, bool PAIRED, bool FOUT, bool STATS>
__global__ __launch_bounds__(TPB) void mconv(
    const unsigned short* __restrict__ inA, int CA,
    const unsigned short* __restrict__ inB, int CB,
    const float* __restrict__ scA, const float* __restrict__ shA,
    const float* __restrict__ scB, const float* __restrict__ shB,
    const unsigned short* __restrict__ wb,
    void* __restrict__ outv,
    float* __restrict__ part2, int NB,
    int N, int Cout, int COP, int CIP, int G) {
  const int tid = threadIdx.x, wv = tid >> 6, l = tid & 63, l15 = l & 15, lg = l >> 4;
  int bx = blockIdx.x;
  const int blkLin = blockIdx.x;
  int w0, h0, d0, n;
  int wvd = wv & 1, jh = wv >> 1, jbase = jh * 4;
  if constexpr (VARIANT == 0) {
    int ntW = G >> 4, ntH = G >> 3, ntD = G >> 1;
    w0 = (bx % ntW) << 4; bx /= ntW;
    h0 = (bx % ntH) << 3; bx /= ntH;
    d0 = (bx % ntD) << 1; n = bx / ntD;
  } else {
    int ntW = G >> 4, ntH = G >> 2, ntD = G >> 2;
    w0 = (bx % ntW) << 4; bx /= ntW;
    h0 = (bx % ntH) << 2; bx /= ntH;
    d0 = (bx % ntD) << 2; n = bx / ntD;
  }
  const int co0 = blockIdx.y * (16 * CO_TILES);
  const int Gin = (VARIANT == 2) ? 2 * G : G;
  const long spin = (long)Gin * Gin * Gin;

  f32x4 acc[CO_TILES][4];
#pragma unroll
  for (int ct = 0; ct < CO_TILES; ++ct)
#pragma unroll
    for (int j = 0; j < 4; ++j) acc[ct][j] = (f32x4){0.f, 0.f, 0.f, 0.f};

  if constexpr (PAIRED) {
    __shared__ unsigned short xs[2 * 728 * 8];
    const unsigned short* src = inA + (long)n * 16 * spin;
    for (int idx = tid; idx < 2 * 720; idx += TPB) {
      int q = idx / 720, pt = idx - q * 720;
      int zw = pt % 18; int zt = pt / 18; int zh = zt % 10; int zd = zt / 10;
      int gd = d0 + zd - 1, gh = h0 + zh - 1, gw = w0 + zw - 1;
      ushort8 v = (ushort8){0,0,0,0,0,0,0,0};
      if ((unsigned)gd < (unsigned)G && (unsigned)gh < (unsigned)G && (unsigned)gw < (unsigned)G)
        v = *(const ushort8*)(src + (((long)gd * G + gh) * G + gw) * 16 + q * 8);
      *(ushort8*)(xs + (q * 728 + pt) * 8) = v;
    }
    __syncthreads();
#pragma unroll 1
    for (int pp = 0; pp < 14; ++pp) {
      short8 A0 = *(const short8*)(wb + ((pp * 32 + l15) * 32) + lg * 8);
      short8 A1 = *(const short8*)(wb + ((pp * 32 + 16 + l15) * 32) + lg * 8);
      int t0 = 2 * pp + (lg >> 1); if (t0 > 26) t0 = 26;
      int dd = t0 / 9 - 1, dh = (t0 / 3) % 3 - 1, dw = t0 % 3 - 1;
      int q = lg & 1;
      int zd = wvd + 1 + dd;
      int base = (q * 728 + (zd * 10 + (1 + dh + jbase)) * 18 + 1 + l15 + dw) * 8;
#pragma unroll
      for (int j = 0; j < 4; ++j) {
        short8 B = *(const short8*)(xs + base + j * (18 * 8));
        acc[0][j] = __builtin_amdgcn_mfma_f32_16x16x32_bf16(A0, B, acc[0][j], 0, 0, 0);
        if (CO_TILES == 2)
          acc[1][j] = __builtin_amdgcn_mfma_f32_16x16x32_bf16(A1, B, acc[1][j], 0, 0, 0);
      }
    }
  } else if constexpr (VARIANT == 0) {
    __shared__ unsigned short xs[4 * 728 * 8];
    const int nch = CIP >> 5;
#pragma unroll 1
    for (int ch = 0; ch < nch; ++ch) {
      int c0 = ch << 5;
      const unsigned short* src; int Cs, cl_;
      const float* scU; const float* shU;
      if (c0 < CA){ src = inA; Cs = CA; cl_ = c0; scU = scA; shU = shA; }
      else        { src = inB; Cs = CB; cl_ = c0 - CA; scU = scB; shU = shB; }
      const unsigned short* sb = src + (long)n * Cs * spin;
      __syncthreads();
      for (int idx = tid; idx < 4 * 720; idx += TPB) {
        int q = idx / 720, pt = idx - q * 720;
        int zw = pt % 18; int zt = pt / 18; int zh = zt % 10; int zd = zt / 10;
        int gd = d0 + zd - 1, gh = h0 + zh - 1, gw = w0 + zw - 1;
        ushort8 v = (ushort8){0,0,0,0,0,0,0,0};
        if ((unsigned)gd < (unsigned)G && (unsigned)gh < (unsigned)G && (unsigned)gw < (unsigned)G) {
          v = *(const ushort8*)(sb + (((long)gd * G + gh) * G + gw) * Cs + cl_ + q * 8);
          if (scU) v = bnApply8(v, scU, shU, cl_ + q * 8);
        }
        *(ushort8*)(xs + (q * 728 + pt) * 8) = v;
      }
      __syncthreads();
#pragma unroll 1
      for (int a = 0; a < 3; ++a) {
        int zd = wvd + a;
        short8 A0[3][3], A1[3][3];
#pragma unroll
        for (int b = 0; b < 3; ++b)
#pragma unroll
          for (int c = 0; c < 3; ++c) {
            int tap = (a * 3 + b) * 3 + c;
            const unsigned short* ap = wb + ((long)tap * COP + co0 + l15) * CIP + c0 + lg * 8;
            A0[b][c] = *(const short8*)ap;
            if (CO_TILES == 2) A1[b][c] = *(const short8*)(ap + 16 * CIP);
          }
#pragma unroll
        for (int sl = 0; sl < 6; ++sl) {
          int sg = jbase + sl;
          int rb = (lg * 728 + (zd * 10 + sg) * 18 + l15) * 8;
          short8 B0 = *(const short8*)(xs + rb);
          short8 B1 = *(const short8*)(xs + rb + 8);
          short8 B2 = *(const short8*)(xs + rb + 16);
#pragma unroll
          for (int b = 0; b < 3; ++b) {
            int j = sl - b;
            if (j >= 0 && j < 4) {
              acc[0][j] = __builtin_amdgcn_mfma_f32_16x16x32_bf16(A0[b][0], B0, acc[0][j], 0, 0, 0);
              acc[0][j] = __builtin_amdgcn_mfma_f32_16x16x32_bf16(A0[b][1], B1, acc[0][j], 0, 0, 0);
              acc[0][j] = __builtin_amdgcn_mfma_f32_16x16x32_bf16(A0[b][2], B2, acc[0][j], 0, 0, 0);
              if (CO_TILES == 2) {
                acc[1][j] = __builtin_amdgcn_mfma_f32_16x16x32_bf16(A1[b][0], B0, acc[1][j], 0, 0, 0);
                acc[1][j] = __builtin_amdgcn_mfma_f32_16x16x32_bf16(A1[b][1], B1, acc[1][j], 0, 0, 0);
                acc[1][j] = __builtin_amdgcn_mfma_f32_16x16x32_bf16(A1[b][2], B2, acc[1][j], 0, 0, 0);
              }
            }
          }
        }
      }
    }
  } else {
    // VARIANT 2: stride-2 conv, direct-global B with fused BN.
    const int nch = CIP >> 5;
#pragma unroll 1
    for (int ch = 0; ch < nch; ++ch) {
      int c0 = ch << 5;
      const unsigned short* src; int Cs, cl_;
      const float* scU; const float* shU;
      if (c0 < CA){ src = inA; Cs = CA; cl_ = c0; scU = scA; shU = shA; }
      else        { src = inB; Cs = CB; cl_ = c0 - CA; scU = scB; shU = shB; }
      const unsigned short* sb = src + (long)n * Cs * spin;
#pragma unroll 1
      for (int a = 0; a < 3; ++a) {
        int gd = 2 * (d0 + wv) + a - 1;
        bool vd = (unsigned)gd < (unsigned)Gin;
#pragma unroll 1
        for (int b = 0; b < 3; ++b) {
#pragma unroll
          for (int c = 0; c < 3; ++c) {
            int tap = (a * 3 + b) * 3 + c;
            const unsigned short* ap = wb + ((long)tap * COP + co0 + l15) * CIP + c0 + lg * 8;
            short8 A0 = *(const short8*)ap;
            short8 A1;
            if (CO_TILES == 2) A1 = *(const short8*)(ap + 16 * CIP);
            int gw = 2 * (w0 + l15) + c - 1;
            bool vdw = vd && ((unsigned)gw < (unsigned)Gin);
#pragma unroll
            for (int j = 0; j < 4; ++j) {
              int gh = 2 * (h0 + j) + b - 1;
              short8 B = (short8){0,0,0,0,0,0,0,0};
              if (vdw && (unsigned)gh < (unsigned)Gin) {
                ushort8 u = *(const ushort8*)(sb + (((long)gd * Gin + gh) * Gin + gw) * Cs + cl_ + lg * 8);
                if (scU) u = bnApply8(u, scU, shU, cl_ + lg * 8);
                B = asS8(u);
              }
              acc[0][j] = __builtin_amdgcn_mfma_f32_16x16x32_bf16(A0, B, acc[0][j], 0, 0, 0);
              if (CO_TILES == 2)
                acc[1][j] = __builtin_amdgcn_mfma_f32_16x16x32_bf16(A1, B, acc[1][j], 0, 0, 0);
            }
          }
        }
      }
    }
  }

  // ---- store ----
  const long spo = (long)G * G * G;
#pragma unroll
  for (int j = 0; j < 4; ++j) {
    long pt;
    if constexpr (VARIANT == 0)
      pt = ((long)(d0 + wvd) * G + (h0 + jbase + j)) * G + (w0 + l15);
    else
      pt = ((long)(d0 + wv) * G + (h0 + j)) * G + (w0 + l15);
    if constexpr (!FOUT) {
      unsigned short* outp = (unsigned short*)outv;
#pragma unroll
      for (int ct = 0; ct < CO_TILES; ++ct) {
        ushort4v pk;
#pragma unroll
        for (int r = 0; r < 4; ++r) pk[r] = f2b(acc[ct][j][r]);
        *(ushort4v*)(outp + ((long)n * spo + pt) * Cout + co0 + ct * 16 + lg * 4) = pk;
      }
    } else {
      float* outp = (float*)outv;
#pragma unroll
      for (int ct = 0; ct < CO_TILES; ++ct)
#pragma unroll
        for (int r = 0; r < 4; ++r) {
          int co = co0 + ct * 16 + lg * 4 + r;
          if (co < Cout) outp[((long)(n * Cout + co)) * spo + pt] = acc[ct][j][r];
        }
    }
  }

  if constexpr (STATS) {
    __shared__ float redS[4][CO_TILES][4][4];
    __shared__ float redQ[4][CO_TILES][4][4];
#pragma unroll
    for (int ct = 0; ct < CO_TILES; ++ct)
#pragma unroll
      for (int r = 0; r < 4; ++r) {
        float s = 0.f, q = 0.f;
#pragma unroll
        for (int j = 0; j < 4; ++j) { float a = acc[ct][j][r]; s += a; q += a * a; }
#pragma unroll
        for (int m = 1; m < 16; m <<= 1) { s += __shfl_xor(s, m); q += __shfl_xor(q, m); }
        if (l15 == 0) { redS[wv][ct][lg][r] = s; redQ[wv][ct][lg][r] = q; }
      }
    __syncthreads();
    if (tid < CO_TILES * 16) {
      int ct = tid >> 4, lg2 = (tid >> 2) & 3, r = tid & 3;
      float s = 0.f, q = 0.f;
#pragma unroll
      for (int w2 = 0; w2 < 4; ++w2) { s += redS[w2][ct][lg2][r]; q += redQ[w2][ct][lg2][r]; }
      int c = co0 + ct * 16 + lg2 * 4 + r;
      long slot = (long)c * NB + blkLin;
      part2[slot * 2] = s; part2[slot * 2 + 1] = q;
    }
  }
}

// ---------------- stats reduce: part2 -> scale/shift ----------------
__global__ void bn_stats2b(const float* __restrict__ part2, const float* __restrict__ g,
                           const float* __restrict__ b, float* __restrict__ sc,
                           float* __restrict__ sh, int NB, float inv_cnt){
  int c = blockIdx.x, tid = threadIdx.x;
  float s = 0.f, q = 0.f;
  for (int i = tid; i < NB; i += TPB) {
    s += part2[((long)c * NB + i) * 2];
    q += part2[((long)c * NB + i) * 2 + 1];
  }
  __shared__ float ss[TPB], qq[TPB];
  ss[tid] = s; qq[tid] = q;
  __syncthreads();
  for (int off = TPB / 2; off > 0; off >>= 1) {
    if (tid < off) { ss[tid] += ss[tid + off]; qq[tid] += qq[tid + off]; }
    __syncthreads();
  }
  if (tid == 0) {
    float m = ss[0] * inv_cnt, v = qq[0] * inv_cnt - m * m;
    float rs = rsqrtf(v + 1e-5f) * g[c];
    sc[c] = rs;
    sh[c] = b[c] - m * rs;
  }
}

extern "C" void kernel_launch(void* const* d_in, const int* in_sizes, int n_in,
                              void* d_out, int out_size, void* d_ws, size_t ws_size,
                              hipStream_t stream) {
  const float* x    = (const float*)d_in[0];
  const float* w0   = (const float*)d_in[1];
  const float* g0   = (const float*)d_in[2];
  const float* b0   = (const float*)d_in[3];
  const float* w1   = (const float*)d_in[4];
  const float* g1   = (const float*)d_in[5];
  const float* b1   = (const float*)d_in[6];
  const float* w2   = (const float*)d_in[7];
  const float* g2   = (const float*)d_in[8];
  const float* b2   = (const float*)d_in[9];
  const float* wt2r = (const float*)d_in[10];
  const float* g2r  = (const float*)d_in[11];
  const float* b2r  = (const float*)d_in[12];
  const float* wt1r = (const float*)d_in[13];
  const float* g1r  = (const float*)d_in[14];
  const float* b1r  = (const float*)d_in[15];
  const float* wt0r = (const float*)d_in[16];
  const float* wt2c = (const float*)d_in[17];
  const float* g2c  = (const float*)d_in[18];
  const float* b2c  = (const float*)d_in[19];
  const float* wt1c = (const float*)d_in[20];
  const float* g1c  = (const float*)d_in[21];
  const float* b1c  = (const float*)d_in[22];
  const float* wt0c = (const float*)d_in[23];

  const int N = 2;
  const long sp64 = 262144, sp32 = 32768, sp16 = 4096;

  // ---- workspace (ushort units), all activations NDHWC bf16 (raw) ----
  unsigned short* W = (unsigned short*)d_ws;
  unsigned short* s1   = W;                       // [2*sp64][32]
  unsigned short* s2   = s1  + 16777216;          // [2*sp32][64]
  unsigned short* s4   = s2  + 4194304;           // [2*sp16][128]
  unsigned short* r32  = s4  + 1048576;           // [2*sp32][64]
  unsigned short* c32  = r32 + 4194304;           // [2*sp32][64]
  unsigned short* r64  = c32 + 4194304;           // [2*sp64][32]
  unsigned short* xt   = r64;                     // alias (dead after conv0)
  unsigned short* c64  = r64 + 16777216;          // [2*sp64][64]
  unsigned short* wb0p = c64 + 33554432;          // 14*32*32
  unsigned short* wb1  = wb0p + 14336;            // 27*64*32
  unsigned short* wb2  = wb1  + 55296;            // 27*128*64
  unsigned short* wb2r = wb2  + 221184;           // 27*64*128
  unsigned short* wb2c = wb2r + 221184;
  unsigned short* wb1r = wb2c + 221184;           // 27*32*64
  unsigned short* wb1c = wb1r + 55296;            // 27*64*128
  unsigned short* wbrec= wb1c + 221184;           // 27*16*32
  unsigned short* wbcl = wbrec+ 13824;            // 27*16*96
  float* part2  = (float*)(wbcl + 41472);         // 131072 f32
  float* part2b = part2 + 131072;                 // 16384 f32
  float* sc_s1  = part2b + 16384; float* sh_s1  = sc_s1 + 128;
  float* sc_s2  = sh_s1 + 128;    float* sh_s2  = sc_s2 + 128;
  float* sc_s4  = sh_s2 + 128;    float* sh_s4  = sc_s4 + 128;
  float* sc_r32 = sh_s4 + 128;    float* sh_r32 = sc_r32 + 128;
  float* sc_c32 = sh_r32 + 128;   float* sh_c32 = sc_c32 + 128;
  float* sc_r64 = sh_c32 + 128;   float* sh_r64 = sc_r64 + 128;
  float* sc_c64 = sh_r64 + 128;   float* sh_c64 = sc_c64 + 128;

  float* out_cl  = (float*)d_out;                 // [2][2][64^3] NCDHW
  float* out_rec = (float*)d_out + 2L * 2 * sp64; // [2][16][64^3]

  // ---- merged weight repack + x transpose ----
  rp_all<<<cdiv_l(1064960, TPB), TPB, 0, stream>>>(
      w0, w1, w2, wt2r, wt2c, wt1r, wt1c, wt0r, wt0c,
      wb0p, wb1, wb2, wb2r, wb2c, wb1r, wb1c, wbrec, wbcl);
  xpose_k<<<2048, TPB, 0, stream>>>(x, xt);

  auto gx0 = [&](int G){ return (unsigned)(N * (G >> 1) * (G >> 3) * (G >> 4)); };
  auto gx  = [&](int G){ return (unsigned)(N * (G >> 2) * (G >> 2) * (G >> 4)); };

  // ---- encoder ----
  // conv0 -> s1 raw (+ stats)
  mconv<0, 2, true, false, true><<<dim3(gx0(64), 1), TPB, 0, stream>>>(
      xt, 16, nullptr, 0, nullptr, nullptr, nullptr, nullptr, wb0p, s1,
      part2, (int)gx0(64), N, 32, 32, 32, 64);
  bn_stats2b<<<32, TPB, 0, stream>>>(part2, g0, b0, sc_s1, sh_s1, (int)gx0(64), 1.f / (float)(2 * sp64));

  // conv1 -> s2 raw (+ stats); BN(s1) fused on B-loads
  mconv<2, 2, false, false, true><<<dim3(gx(32), 2), TPB, 0, stream>>>(
      s1, 32, nullptr, 0, sc_s1, sh_s1, nullptr, nullptr, wb1, s2,
      part2, (int)gx(32), N, 64, 64, 32, 32);
  bn_stats2b<<<64, TPB, 0, stream>>>(part2, g1, b1, sc_s2, sh_s2, (int)gx(32), 1.f / (float)(2 * sp32));

  // conv2 -> s4 raw (+ stats); BN(s2) fused on B-loads
  mconv<2, 1, false, false, true><<<dim3(gx(16), 8), TPB, 0, stream>>>(
      s2, 64, nullptr, 0, sc_s2, sh_s2, nullptr, nullptr, wb2, s4,
      part2, (int)gx(16), N, 128, 128, 64, 16);
  bn_stats2b<<<128, TPB, 0, stream>>>(part2, g2, b2, sc_s4, sh_s4, (int)gx(16), 1.f / (float)(2 * sp16));

  // ---- level-2 dual tconv (s4 staged once) -> r32, c32 (+ both stats) ----
  tconv_dual<<<dim3(gx(16), 2, 4), TPB, 0, stream>>>(
      s4, 128, sc_s4, sh_s4, wb2r, wb2c, r32, c32, part2, part2b, (int)gx(16) * 4,
      N, 64, 64, 128, 16);
  bn_stats2b<<<64, TPB, 0, stream>>>(part2, g2r, b2r, sc_r32, sh_r32, (int)gx(16) * 4, 1.f / (float)(2 * sp32));
  bn_stats2b<<<64, TPB, 0, stream>>>(part2b, g2c, b2c, sc_c32, sh_c32, (int)gx(16) * 4, 1.f / (float)(2 * sp32));

  // ---- level-1 tconvs (32 -> 64), quadrants (+ stats) ----
  tconv_quad<2, true><<<dim3(gx(32), 1, 4), TPB, 0, stream>>>(
      r32, 64, nullptr, 0, sc_r32, sh_r32, nullptr, nullptr, wb1r, r64,
      part2, (int)gx(32) * 4, N, 32, 32, 64, 32);
  bn_stats2b<<<32, TPB, 0, stream>>>(part2, g1r, b1r, sc_r64, sh_r64, (int)gx(32) * 4, 1.f / (float)(2 * sp64));
  tconv_quad<4, true><<<dim3(gx(32), 1, 4), TPB, 0, stream>>>(
      c32, 64, s2, 64, sc_c32, sh_c32, sc_s2, sh_s2, wb1c, c64,
      part2, (int)gx(32) * 4, N, 64, 64, 128, 32);
  bn_stats2b<<<64, TPB, 0, stream>>>(part2, g1c, b1c, sc_c64, sh_c64, (int)gx(32) * 4, 1.f / (float)(2 * sp64));

  // ---- level-0 stride-1 convs -> fp32 outputs; BN fused on both inputs ----
  mconv<0, 1, false, true, false><<<dim3(gx0(64), 1), TPB, 0, stream>>>(
      r64, 32, nullptr, 0, sc_r64, sh_r64, nullptr, nullptr, wbrec, out_rec,
      nullptr, 0, N, 16, 16, 32, 64);
  mconv<0, 1, false, true, false><<<dim3(gx0(64), 1), TPB, 0, stream>>>(
      c64, 64, s1, 32, sc_c64, sh_c64, sc_s1, sh_s1, wbcl, out_cl,
      nullptr, 0, N, 2, 16, 96, 64);
}

// Round 16
// 564.960 us; speedup vs baseline: 1.0639x; 1.0639x over previous
//
#include <hip/hip_runtime.h>
#include <hip/hip_bf16.h>

// ---------------------------------------------------------------------------
// UNet3D dense forward, round 16: exact revert to R14 (best, 570us).
//  - BN stats fused into producers; s1/s2 normalized in-place once (cheaper
//    than per-consumer fused applies, verified by R15 regression).
//  - tconv2r+tconv2c merged into dual-head kernel; merged weight repack.
// ---------------------------------------------------------------------------

using bf16 = __hip_bfloat16;
using ushort4v = __attribute__((ext_vector_type(4))) unsigned short;
using ushort8  = __attribute__((ext_vector_type(8))) unsigned short;
using short8   = __attribute__((ext_vector_type(8))) short;
using f32x4    = __attribute__((ext_vector_type(4))) float;
using float4v  = __attribute__((ext_vector_type(4))) float;

#define TPB 256

static inline int cdiv_l(long a, int b){ return (int)((a + b - 1) / b); }

__device__ __forceinline__ float b2f(unsigned short u){
  union { unsigned int i; float f; } v; v.i = ((unsigned int)u) << 16; return v.f;
}
__device__ __forceinline__ unsigned short f2b(float f){
  union { bf16 h; unsigned short u; } v; v.h = __float2bfloat16(f); return v.u;
}
__device__ __forceinline__ ushort8 bnApply8(ushort8 v, const float* sc, const float* sh, int c){
  float4v s0 = *(const float4v*)(sc + c), s1v = *(const float4v*)(sc + c + 4);
  float4v h0 = *(const float4v*)(sh + c), h1v = *(const float4v*)(sh + c + 4);
  ushort8 r;
#pragma unroll
  for (int j = 0; j < 4; ++j){ float y = b2f(v[j]) * s0[j] + h0[j]; r[j] = f2b(y > 0.f ? y : 0.f); }
#pragma unroll
  for (int j = 0; j < 4; ++j){ float y = b2f(v[j+4]) * s1v[j] + h1v[j]; r[j+4] = f2b(y > 0.f ? y : 0.f); }
  return r;
}

// ---------------- merged weight repack ----------------
__global__ void rp_all(const float* __restrict__ w0, const float* __restrict__ w1,
                       const float* __restrict__ w2, const float* __restrict__ wt2r,
                       const float* __restrict__ wt2c, const float* __restrict__ wt1r,
                       const float* __restrict__ wt1c, const float* __restrict__ wt0r,
                       const float* __restrict__ wt0c,
                       unsigned short* __restrict__ wb0p, unsigned short* __restrict__ wb1,
                       unsigned short* __restrict__ wb2, unsigned short* __restrict__ wb2r,
                       unsigned short* __restrict__ wb2c, unsigned short* __restrict__ wb1r,
                       unsigned short* __restrict__ wb1c, unsigned short* __restrict__ wbrec,
                       unsigned short* __restrict__ wbcl){
  int idx = blockIdx.x * TPB + threadIdx.x;
  auto enc = [](const float* w, unsigned short* d, int i, int Cin, int Cout){
    int ci = i % Cin; int t = i / Cin; int co = t % Cout; int tap = t / Cout;
    d[i] = f2b(w[((long)co * Cin + ci) * 27 + tap]);
  };
  auto dec = [](const float* w, unsigned short* d, int i, int Cin, int Cout, int CIP, int COP){
    int ci = i % CIP; int t = i / CIP; int co = t % COP; int tap = t / COP;
    float v = (ci < Cin && co < Cout) ? w[((long)tap * Cin + ci) * Cout + co] : 0.f;
    d[i] = f2b(v);
  };
  if (idx < 14336) {
    int i = idx;
    int k = i & 31; int t = i >> 5; int co = t & 31; int pp = t >> 5;
    int tap = pp * 2 + (k >> 4); int ci = k & 15;
    float v = (tap < 27) ? w0[((long)co * 16 + ci) * 27 + tap] : 0.f;
    wb0p[i] = f2b(v);
  }
  else if (idx <   69632) enc(w1,  wb1,  idx - 14336,  32, 64);
  else if (idx <  290816) enc(w2,  wb2,  idx - 69632,  64, 128);
  else if (idx <  512000) dec(wt2r, wb2r, idx - 290816, 128, 64, 128, 64);
  else if (idx <  733184) dec(wt2c, wb2c, idx - 512000, 128, 64, 128, 64);
  else if (idx <  788480) dec(wt1r, wb1r, idx - 733184,  64, 32,  64, 32);
  else if (idx < 1009664) dec(wt1c, wb1c, idx - 788480, 128, 64, 128, 64);
  else if (idx < 1023488) dec(wt0r, wbrec, idx - 1009664, 32, 16,  32, 16);
  else if (idx < 1064960) dec(wt0c, wbcl, idx - 1023488, 96,  2,  96, 16);
}

// ---------------- x transpose: NCDHW fp32 -> NDHWC bf16 (C=16) ----------------
__global__ void xpose_k(const float* __restrict__ x, unsigned short* __restrict__ xt){
  __shared__ float l[16][257];
  int t = threadIdx.x;
  long p0 = (long)blockIdx.x * 256;
  int n = (int)(p0 >> 18);
  long off = p0 & 262143;
  const float* xb = x + ((long)n * 16) * 262144 + off;
#pragma unroll
  for (int c = 0; c < 16; ++c) l[c][t] = xb[(long)c * 262144 + t];
  __syncthreads();
  ushort8 u0, u1;
#pragma unroll
  for (int k = 0; k < 8; ++k){ u0[k] = f2b(l[k][t]); u1[k] = f2b(l[k + 8][t]); }
  unsigned short* o = xt + (p0 + t) * 16;
  *(ushort8*)o = u0; *(ushort8*)(o + 8) = u1;
}

// ---------------- quadrant stride-2 tconv, dbuf LDS, optional fused stats ----
template <int CO_TILES, bool STATS>
__global__ __launch_bounds__(TPB, 2) void tconv_quad(
    const unsigned short* __restrict__ inA, int CA,
    const unsigned short* __restrict__ inB, int CB,
    const float* __restrict__ scA, const float* __restrict__ shA,
    const unsigned short* __restrict__ wb,
    unsigned short* __restrict__ out,
    float* __restrict__ part2, int NB,
    int N, int Cout, int COP, int CIP, int G) {
  __shared__ unsigned short xs[2][4 * 432 * 8];
  const int tid = threadIdx.x, wv = tid >> 6, l = tid & 63, l15 = l & 15, lg = l >> 4;
  int ntW = G >> 4, ntH = G >> 2, ntD = G >> 2;
  int bx = blockIdx.x;
  const int blkLin = blockIdx.x * 4 + blockIdx.z;
  int w0 = (bx % ntW) << 4; bx /= ntW;
  int h0 = (bx % ntH) << 2; bx /= ntH;
  int d0 = (bx % ntD) << 2; int n = bx / ntD;
  const int co0 = blockIdx.y * (16 * CO_TILES);
  const int quad = blockIdx.z;
  const int pd = (quad >> 1) & 1, ph = quad & 1;
  const long spin = (long)G * G * G;

  int nkd, kd_[2], dd_[2], nkh, kh_[2], dh_[2];
  if (pd){ nkd=1; kd_[0]=1; dd_[0]=0; } else { nkd=2; kd_[0]=0; dd_[0]=-1; kd_[1]=2; dd_[1]=0; }
  if (ph){ nkh=1; kh_[0]=1; dh_[0]=0; } else { nkh=2; kh_[0]=0; dh_[0]=-1; kh_[1]=2; dh_[1]=0; }

  f32x4 acc[CO_TILES][4][2];
#pragma unroll
  for (int ct = 0; ct < CO_TILES; ++ct)
#pragma unroll
    for (int j = 0; j < 4; ++j)
#pragma unroll
      for (int p = 0; p < 2; ++p) acc[ct][j][p] = (f32x4){0.f, 0.f, 0.f, 0.f};

  auto stage = [&](int ch, int buf) {
    int c0 = ch << 5;
    const unsigned short* src; int Cs, cl_; bool useBN;
    if (c0 < CA){ src = inA; Cs = CA; cl_ = c0; useBN = (scA != nullptr); }
    else        { src = inB; Cs = CB; cl_ = c0 - CA; useBN = false; }
    const unsigned short* sb = src + (long)n * Cs * spin;
    unsigned short* xb = &xs[buf][0];
    for (int idx = tid; idx < 4 * 425; idx += TPB) {
      int q = idx / 425, pt = idx - q * 425;
      int zw = pt % 17; int zt = pt / 17; int zh = zt % 5; int zd = zt / 5;
      int gd = d0 + zd - 1, gh = h0 + zh - 1, gw = w0 + zw - 1;
      ushort8 v = (ushort8){0,0,0,0,0,0,0,0};
      if ((unsigned)gd < (unsigned)G && (unsigned)gh < (unsigned)G && (unsigned)gw < (unsigned)G) {
        v = *(const ushort8*)(sb + (((long)gd * G + gh) * G + gw) * Cs + cl_ + q * 8);
        if (useBN) v = bnApply8(v, scA, shA, cl_ + q * 8);
      }
      *(ushort8*)(xb + (q * 432 + pt) * 8) = v;
    }
  };

  const int nch = CIP >> 5;
  stage(0, 0);
  __syncthreads();
#pragma unroll 1
  for (int ch = 0; ch < nch; ++ch) {
    int cur = ch & 1;
    int c0 = ch << 5;
    if (ch + 1 < nch) stage(ch + 1, cur ^ 1);
    const unsigned short* xr = &xs[cur][0];
#pragma unroll 1
    for (int a = 0; a < nkd; ++a) {
      int zd = wv + 1 + dd_[a];
#pragma unroll 1
      for (int b = 0; b < nkh; ++b) {
        int tapb = (kd_[a] * 3 + kh_[b]) * 3;
        const unsigned short* ap = wb + ((long)tapb * COP + co0 + l15) * CIP + c0 + lg * 8;
        long tstride = (long)COP * CIP;
        short8 Ak0[CO_TILES], Ak1[CO_TILES], Ak2[CO_TILES];
#pragma unroll
        for (int ct = 0; ct < CO_TILES; ++ct) {
          Ak0[ct] = *(const short8*)(ap + ct * 16 * CIP);
          Ak1[ct] = *(const short8*)(ap + tstride + ct * 16 * CIP);
          Ak2[ct] = *(const short8*)(ap + 2 * tstride + ct * 16 * CIP);
        }
        int zh0 = 1 + dh_[b];
#pragma unroll
        for (int j = 0; j < 4; ++j) {
          int basept = (zd * 5 + (j + zh0)) * 17 + l15;
          short8 Bm = *(const short8*)(xr + (lg * 432 + basept) * 8);
          short8 B0 = *(const short8*)(xr + (lg * 432 + basept + 1) * 8);
#pragma unroll
          for (int ct = 0; ct < CO_TILES; ++ct) {
            acc[ct][j][0] = __builtin_amdgcn_mfma_f32_16x16x32_bf16(Ak0[ct], Bm, acc[ct][j][0], 0, 0, 0);
            acc[ct][j][0] = __builtin_amdgcn_mfma_f32_16x16x32_bf16(Ak2[ct], B0, acc[ct][j][0], 0, 0, 0);
            acc[ct][j][1] = __builtin_amdgcn_mfma_f32_16x16x32_bf16(Ak1[ct], B0, acc[ct][j][1], 0, 0, 0);
          }
        }
      }
    }
    __syncthreads();
  }

  // ---- dense store ----
  int Gout = 2 * G; long spo = (long)Gout * Gout * Gout;
  int od = 2 * (d0 + wv) + pd;
#pragma unroll
  for (int j = 0; j < 4; ++j) {
    int oh = 2 * (h0 + j) + ph;
#pragma unroll
    for (int p = 0; p < 2; ++p) {
      int ow = 2 * (w0 + l15) + p;
      long pt = ((long)od * Gout + oh) * Gout + ow;
#pragma unroll
      for (int ct = 0; ct < CO_TILES; ++ct) {
        ushort4v pk;
#pragma unroll
        for (int r = 0; r < 4; ++r) pk[r] = f2b(acc[ct][j][p][r]);
        *(ushort4v*)(out + ((long)n * spo + pt) * Cout + co0 + ct * 16 + lg * 4) = pk;
      }
    }
  }

  if constexpr (STATS) {
    __shared__ float redS[4][CO_TILES][4][4];
    __shared__ float redQ[4][CO_TILES][4][4];
#pragma unroll
    for (int ct = 0; ct < CO_TILES; ++ct)
#pragma unroll
      for (int r = 0; r < 4; ++r) {
        float s = 0.f, q = 0.f;
#pragma unroll
        for (int j = 0; j < 4; ++j)
#pragma unroll
          for (int p = 0; p < 2; ++p) { float a = acc[ct][j][p][r]; s += a; q += a * a; }
#pragma unroll
        for (int m = 1; m < 16; m <<= 1) { s += __shfl_xor(s, m); q += __shfl_xor(q, m); }
        if (l15 == 0) { redS[wv][ct][lg][r] = s; redQ[wv][ct][lg][r] = q; }
      }
    __syncthreads();
    if (tid < CO_TILES * 16) {
      int ct = tid >> 4, lg2 = (tid >> 2) & 3, r = tid & 3;
      float s = 0.f, q = 0.f;
#pragma unroll
      for (int w2 = 0; w2 < 4; ++w2) { s += redS[w2][ct][lg2][r]; q += redQ[w2][ct][lg2][r]; }
      int c = co0 + ct * 16 + lg2 * 4 + r;
      long slot = (long)c * NB + blkLin;
      part2[slot * 2] = s; part2[slot * 2 + 1] = q;
    }
  }
}

// ---------------- dual-head quadrant tconv2 (shared s4 staging) ------------
__global__ __launch_bounds__(TPB) void tconv_dual(
    const unsigned short* __restrict__ in, int CI,
    const float* __restrict__ scA, const float* __restrict__ shA,
    const unsigned short* __restrict__ wbA, const unsigned short* __restrict__ wbB,
    unsigned short* __restrict__ outA, unsigned short* __restrict__ outB,
    float* __restrict__ p2A, float* __restrict__ p2B, int NB,
    int N, int Cout, int COP, int CIP, int G) {
  const int CT = 2;
  __shared__ unsigned short xs[4 * 432 * 8];
  const int tid = threadIdx.x, wv = tid >> 6, l = tid & 63, l15 = l & 15, lg = l >> 4;
  int ntW = G >> 4, ntH = G >> 2, ntD = G >> 2;
  int bx = blockIdx.x;
  const int blkLin = blockIdx.x * 4 + blockIdx.z;
  int w0 = (bx % ntW) << 4; bx /= ntW;
  int h0 = (bx % ntH) << 2; bx /= ntH;
  int d0 = (bx % ntD) << 2; int n = bx / ntD;
  const int co0 = blockIdx.y * (16 * CT);
  const int quad = blockIdx.z;
  const int pd = (quad >> 1) & 1, ph = quad & 1;
  const long spin = (long)G * G * G;

  int nkd, kd_[2], dd_[2], nkh, kh_[2], dh_[2];
  if (pd){ nkd=1; kd_[0]=1; dd_[0]=0; } else { nkd=2; kd_[0]=0; dd_[0]=-1; kd_[1]=2; dd_[1]=0; }
  if (ph){ nkh=1; kh_[0]=1; dh_[0]=0; } else { nkh=2; kh_[0]=0; dh_[0]=-1; kh_[1]=2; dh_[1]=0; }

  f32x4 acc[2][CT][4][2];
#pragma unroll
  for (int h = 0; h < 2; ++h)
#pragma unroll
    for (int ct = 0; ct < CT; ++ct)
#pragma unroll
      for (int j = 0; j < 4; ++j)
#pragma unroll
        for (int p = 0; p < 2; ++p) acc[h][ct][j][p] = (f32x4){0.f, 0.f, 0.f, 0.f};

  const int nch = CIP >> 5;
#pragma unroll 1
  for (int ch = 0; ch < nch; ++ch) {
    int c0 = ch << 5;
    const unsigned short* sb = in + (long)n * CI * spin;
    __syncthreads();
    for (int idx = tid; idx < 4 * 425; idx += TPB) {
      int q = idx / 425, pt = idx - q * 425;
      int zw = pt % 17; int zt = pt / 17; int zh = zt % 5; int zd = zt / 5;
      int gd = d0 + zd - 1, gh = h0 + zh - 1, gw = w0 + zw - 1;
      ushort8 v = (ushort8){0,0,0,0,0,0,0,0};
      if ((unsigned)gd < (unsigned)G && (unsigned)gh < (unsigned)G && (unsigned)gw < (unsigned)G) {
        v = *(const ushort8*)(sb + (((long)gd * G + gh) * G + gw) * CI + c0 + q * 8);
        v = bnApply8(v, scA, shA, c0 + q * 8);
      }
      *(ushort8*)(xs + (q * 432 + pt) * 8) = v;
    }
    __syncthreads();
#pragma unroll 1
    for (int a = 0; a < nkd; ++a) {
      int zd = wv + 1 + dd_[a];
#pragma unroll 1
      for (int b = 0; b < nkh; ++b) {
        int tapb = (kd_[a] * 3 + kh_[b]) * 3;
        long tstride = (long)COP * CIP;
        long abase = ((long)tapb * COP + co0 + l15) * CIP + c0 + lg * 8;
        int zh0 = 1 + dh_[b];
#pragma unroll
        for (int h = 0; h < 2; ++h) {
          const unsigned short* ap = (h == 0 ? wbA : wbB) + abase;
          short8 Ak0[CT], Ak1[CT], Ak2[CT];
#pragma unroll
          for (int ct = 0; ct < CT; ++ct) {
            Ak0[ct] = *(const short8*)(ap + ct * 16 * CIP);
            Ak1[ct] = *(const short8*)(ap + tstride + ct * 16 * CIP);
            Ak2[ct] = *(const short8*)(ap + 2 * tstride + ct * 16 * CIP);
          }
#pragma unroll
          for (int j = 0; j < 4; ++j) {
            int basept = (zd * 5 + (j + zh0)) * 17 + l15;
            short8 Bm = *(const short8*)(xs + (lg * 432 + basept) * 8);
            short8 B0 = *(const short8*)(xs + (lg * 432 + basept + 1) * 8);
#pragma unroll
            for (int ct = 0; ct < CT; ++ct) {
              acc[h][ct][j][0] = __builtin_amdgcn_mfma_f32_16x16x32_bf16(Ak0[ct], Bm, acc[h][ct][j][0], 0, 0, 0);
              acc[h][ct][j][0] = __builtin_amdgcn_mfma_f32_16x16x32_bf16(Ak2[ct], B0, acc[h][ct][j][0], 0, 0, 0);
              acc[h][ct][j][1] = __builtin_amdgcn_mfma_f32_16x16x32_bf16(Ak1[ct], B0, acc[h][ct][j][1], 0, 0, 0);
            }
          }
        }
      }
    }
  }

  // ---- dense store (both heads) ----
  int Gout = 2 * G; long spo = (long)Gout * Gout * Gout;
  int od = 2 * (d0 + wv) + pd;
#pragma unroll
  for (int j = 0; j < 4; ++j) {
    int oh = 2 * (h0 + j) + ph;
#pragma unroll
    for (int p = 0; p < 2; ++p) {
      int ow = 2 * (w0 + l15) + p;
      long pt = ((long)od * Gout + oh) * Gout + ow;
#pragma unroll
      for (int h = 0; h < 2; ++h) {
        unsigned short* o = h == 0 ? outA : outB;
#pragma unroll
        for (int ct = 0; ct < CT; ++ct) {
          ushort4v pk;
#pragma unroll
          for (int r = 0; r < 4; ++r) pk[r] = f2b(acc[h][ct][j][p][r]);
          *(ushort4v*)(o + ((long)n * spo + pt) * Cout + co0 + ct * 16 + lg * 4) = pk;
        }
      }
    }
  }

  // ---- stats, two rounds ----
  __shared__ float redS[4][CT][4][4];
  __shared__ float redQ[4][CT][4][4];
#pragma unroll 1
  for (int h = 0; h < 2; ++h) {
    __syncthreads();
#pragma unroll
    for (int ct = 0; ct < CT; ++ct)
#pragma unroll
      for (int r = 0; r < 4; ++r) {
        float s = 0.f, q = 0.f;
#pragma unroll
        for (int j = 0; j < 4; ++j)
#pragma unroll
          for (int p = 0; p < 2; ++p) { float a = acc[h][ct][j][p][r]; s += a; q += a * a; }
#pragma unroll
        for (int m = 1; m < 16; m <<= 1) { s += __shfl_xor(s, m); q += __shfl_xor(q, m); }
        if (l15 == 0) { redS[wv][ct][lg][r] = s; redQ[wv][ct][lg][r] = q; }
      }
    __syncthreads();
    if (tid < CT * 16) {
      int ct = tid >> 4, lg2 = (tid >> 2) & 3, r = tid & 3;
      float s = 0.f, q = 0.f;
#pragma unroll
      for (int w2 = 0; w2 < 4; ++w2) { s += redS[w2][ct][lg2][r]; q += redQ[w2][ct][lg2][r]; }
      int c = co0 + ct * 16 + lg2 * 4 + r;
      long slot = (long)c * NB + blkLin;
      float* p2 = h == 0 ? p2A : p2B;
      p2[slot * 2] = s; p2[slot * 2 + 1] = q;
    }
  }
}

// ---------------- unified NDHWC MFMA conv ----------------
// VARIANT 0 / PAIRED: stride-1 conv, LDS-staged, tile 2d x 8h x 16w.
// VARIANT 2: stride-2 conv, direct-global B, tile 4d x 4h x 16w.
template <int VARIANT, int CO_TILES, bool PAIRED, bool FOUT, bool STATS>
__global__ __launch_bounds__(TPB) void mconv(
    const unsigned short* __restrict__ inA, int CA,
    const unsigned short* __restrict__ inB, int CB,
    const float* __restrict__ scA, const float* __restrict__ shA,
    const unsigned short* __restrict__ wb,
    void* __restrict__ outv,
    float* __restrict__ part2, int NB,
    int N, int Cout, int COP, int CIP, int G) {
  const int tid = threadIdx.x, wv = tid >> 6, l = tid & 63, l15 = l & 15, lg = l >> 4;
  int bx = blockIdx.x;
  const int blkLin = blockIdx.x;
  int w0, h0, d0, n;
  int wvd = wv & 1, jh = wv >> 1, jbase = jh * 4;
  if constexpr (VARIANT == 0) {
    int ntW = G >> 4, ntH = G >> 3, ntD = G >> 1;
    w0 = (bx % ntW) << 4; bx /= ntW;
    h0 = (bx % ntH) << 3; bx /= ntH;
    d0 = (bx % ntD) << 1; n = bx / ntD;
  } else {
    int ntW = G >> 4, ntH = G >> 2, ntD = G >> 2;
    w0 = (bx % ntW) << 4; bx /= ntW;
    h0 = (bx % ntH) << 2; bx /= ntH;
    d0 = (bx % ntD) << 2; n = bx / ntD;
  }
  const int co0 = blockIdx.y * (16 * CO_TILES);
  const int Gin = (VARIANT == 2) ? 2 * G : G;
  const long spin = (long)Gin * Gin * Gin;

  f32x4 acc[CO_TILES][4];
#pragma unroll
  for (int ct = 0; ct < CO_TILES; ++ct)
#pragma unroll
    for (int j = 0; j < 4; ++j) acc[ct][j] = (f32x4){0.f, 0.f, 0.f, 0.f};

  if constexpr (PAIRED) {
    __shared__ unsigned short xs[2 * 728 * 8];
    const unsigned short* src = inA + (long)n * 16 * spin;
    for (int idx = tid; idx < 2 * 720; idx += TPB) {
      int q = idx / 720, pt = idx - q * 720;
      int zw = pt % 18; int zt = pt / 18; int zh = zt % 10; int zd = zt / 10;
      int gd = d0 + zd - 1, gh = h0 + zh - 1, gw = w0 + zw - 1;
      ushort8 v = (ushort8){0,0,0,0,0,0,0,0};
      if ((unsigned)gd < (unsigned)G && (unsigned)gh < (unsigned)G && (unsigned)gw < (unsigned)G)
        v = *(const ushort8*)(src + (((long)gd * G + gh) * G + gw) * 16 + q * 8);
      *(ushort8*)(xs + (q * 728 + pt) * 8) = v;
    }
    __syncthreads();
#pragma unroll 1
    for (int pp = 0; pp < 14; ++pp) {
      short8 A0 = *(const short8*)(wb + ((pp * 32 + l15) * 32) + lg * 8);
      short8 A1 = *(const short8*)(wb + ((pp * 32 + 16 + l15) * 32) + lg * 8);
      int t0 = 2 * pp + (lg >> 1); if (t0 > 26) t0 = 26;
      int dd = t0 / 9 - 1, dh = (t0 / 3) % 3 - 1, dw = t0 % 3 - 1;
      int q = lg & 1;
      int zd = wvd + 1 + dd;
      int base = (q * 728 + (zd * 10 + (1 + dh + jbase)) * 18 + 1 + l15 + dw) * 8;
#pragma unroll
      for (int j = 0; j < 4; ++j) {
        short8 B = *(const short8*)(xs + base + j * (18 * 8));
        acc[0][j] = __builtin_amdgcn_mfma_f32_16x16x32_bf16(A0, B, acc[0][j], 0, 0, 0);
        if (CO_TILES == 2)
          acc[1][j] = __builtin_amdgcn_mfma_f32_16x16x32_bf16(A1, B, acc[1][j], 0, 0, 0);
      }
    }
  } else if constexpr (VARIANT == 0) {
    __shared__ unsigned short xs[4 * 728 * 8];
    const int nch = CIP >> 5;
#pragma unroll 1
    for (int ch = 0; ch < nch; ++ch) {
      int c0 = ch << 5;
      const unsigned short* src; int Cs, cl_; bool useBN;
      if (c0 < CA){ src = inA; Cs = CA; cl_ = c0; useBN = (scA != nullptr); }
      else        { src = inB; Cs = CB; cl_ = c0 - CA; useBN = false; }
      const unsigned short* sb = src + (long)n * Cs * spin;
      __syncthreads();
      for (int idx = tid; idx < 4 * 720; idx += TPB) {
        int q = idx / 720, pt = idx - q * 720;
        int zw = pt % 18; int zt = pt / 18; int zh = zt % 10; int zd = zt / 10;
        int gd = d0 + zd - 1, gh = h0 + zh - 1, gw = w0 + zw - 1;
        ushort8 v = (ushort8){0,0,0,0,0,0,0,0};
        if ((unsigned)gd < (unsigned)G && (unsigned)gh < (unsigned)G && (unsigned)gw < (unsigned)G) {
          v = *(const ushort8*)(sb + (((long)gd * G + gh) * G + gw) * Cs + cl_ + q * 8);
          if (useBN) v = bnApply8(v, scA, shA, cl_ + q * 8);
        }
        *(ushort8*)(xs + (q * 728 + pt) * 8) = v;
      }
      __syncthreads();
#pragma unroll 1
      for (int a = 0; a < 3; ++a) {
        int zd = wvd + a;
        short8 A0[3][3], A1[3][3];
#pragma unroll
        for (int b = 0; b < 3; ++b)
#pragma unroll
          for (int c = 0; c < 3; ++c) {
            int tap = (a * 3 + b) * 3 + c;
            const unsigned short* ap = wb + ((long)tap * COP + co0 + l15) * CIP + c0 + lg * 8;
            A0[b][c] = *(const short8*)ap;
            if (CO_TILES == 2) A1[b][c] = *(const short8*)(ap + 16 * CIP);
          }
#pragma unroll
        for (int sl = 0; sl < 6; ++sl) {
          int sg = jbase + sl;
          int rb = (lg * 728 + (zd * 10 + sg) * 18 + l15) * 8;
          short8 B0 = *(const short8*)(xs + rb);
          short8 B1 = *(const short8*)(xs + rb + 8);
          short8 B2 = *(const short8*)(xs + rb + 16);
#pragma unroll
          for (int b = 0; b < 3; ++b) {
            int j = sl - b;
            if (j >= 0 && j < 4) {
              acc[0][j] = __builtin_amdgcn_mfma_f32_16x16x32_bf16(A0[b][0], B0, acc[0][j], 0, 0, 0);
              acc[0][j] = __builtin_amdgcn_mfma_f32_16x16x32_bf16(A0[b][1], B1, acc[0][j], 0, 0, 0);
              acc[0][j] = __builtin_amdgcn_mfma_f32_16x16x32_bf16(A0[b][2], B2, acc[0][j], 0, 0, 0);
              if (CO_TILES == 2) {
                acc[1][j] = __builtin_amdgcn_mfma_f32_16x16x32_bf16(A1[b][0], B0, acc[1][j], 0, 0, 0);
                acc[1][j] = __builtin_amdgcn_mfma_f32_16x16x32_bf16(A1[b][1], B1, acc[1][j], 0, 0, 0);
                acc[1][j] = __builtin_amdgcn_mfma_f32_16x16x32_bf16(A1[b][2], B2, acc[1][j], 0, 0, 0);
              }
            }
          }
        }
      }
    }
  } else {
    const int nch = CIP >> 5;
#pragma unroll 1
    for (int ch = 0; ch < nch; ++ch) {
      int c0 = ch << 5;
      const unsigned short* src; int Cs, cl_;
      if (c0 < CA){ src = inA; Cs = CA; cl_ = c0; } else { src = inB; Cs = CB; cl_ = c0 - CA; }
      const unsigned short* sb = src + (long)n * Cs * spin;
#pragma unroll 1
      for (int a = 0; a < 3; ++a) {
        int gd = 2 * (d0 + wv) + a - 1;
        bool vd = (unsigned)gd < (unsigned)Gin;
#pragma unroll 1
        for (int b = 0; b < 3; ++b) {
#pragma unroll
          for (int c = 0; c < 3; ++c) {
            int tap = (a * 3 + b) * 3 + c;
            const unsigned short* ap = wb + ((long)tap * COP + co0 + l15) * CIP + c0 + lg * 8;
            short8 A0 = *(const short8*)ap;
            short8 A1;
            if (CO_TILES == 2) A1 = *(const short8*)(ap + 16 * CIP);
            int gw = 2 * (w0 + l15) + c - 1;
            bool vdw = vd && ((unsigned)gw < (unsigned)Gin);
#pragma unroll
            for (int j = 0; j < 4; ++j) {
              int gh = 2 * (h0 + j) + b - 1;
              short8 B = (short8){0,0,0,0,0,0,0,0};
              if (vdw && (unsigned)gh < (unsigned)Gin)
                B = *(const short8*)(sb + (((long)gd * Gin + gh) * Gin + gw) * Cs + cl_ + lg * 8);
              acc[0][j] = __builtin_amdgcn_mfma_f32_16x16x32_bf16(A0, B, acc[0][j], 0, 0, 0);
              if (CO_TILES == 2)
                acc[1][j] = __builtin_amdgcn_mfma_f32_16x16x32_bf16(A1, B, acc[1][j], 0, 0, 0);
            }
          }
        }
      }
    }
  }

  // ---- store ----
  const long spo = (long)G * G * G;
#pragma unroll
  for (int j = 0; j < 4; ++j) {
    long pt;
    if constexpr (VARIANT == 0)
      pt = ((long)(d0 + wvd) * G + (h0 + jbase + j)) * G + (w0 + l15);
    else
      pt = ((long)(d0 + wv) * G + (h0 + j)) * G + (w0 + l15);
    if constexpr (!FOUT) {
      unsigned short* outp = (unsigned short*)outv;
#pragma unroll
      for (int ct = 0; ct < CO_TILES; ++ct) {
        ushort4v pk;
#pragma unroll
        for (int r = 0; r < 4; ++r) pk[r] = f2b(acc[ct][j][r]);
        *(ushort4v*)(outp + ((long)n * spo + pt) * Cout + co0 + ct * 16 + lg * 4) = pk;
      }
    } else {
      float* outp = (float*)outv;
#pragma unroll
      for (int ct = 0; ct < CO_TILES; ++ct)
#pragma unroll
        for (int r = 0; r < 4; ++r) {
          int co = co0 + ct * 16 + lg * 4 + r;
          if (co < Cout) outp[((long)(n * Cout + co)) * spo + pt] = acc[ct][j][r];
        }
    }
  }

  if constexpr (STATS) {
    __shared__ float redS[4][CO_TILES][4][4];
    __shared__ float redQ[4][CO_TILES][4][4];
#pragma unroll
    for (int ct = 0; ct < CO_TILES; ++ct)
#pragma unroll
      for (int r = 0; r < 4; ++r) {
        float s = 0.f, q = 0.f;
#pragma unroll
        for (int j = 0; j < 4; ++j) { float a = acc[ct][j][r]; s += a; q += a * a; }
#pragma unroll
        for (int m = 1; m < 16; m <<= 1) { s += __shfl_xor(s, m); q += __shfl_xor(q, m); }
        if (l15 == 0) { redS[wv][ct][lg][r] = s; redQ[wv][ct][lg][r] = q; }
      }
    __syncthreads();
    if (tid < CO_TILES * 16) {
      int ct = tid >> 4, lg2 = (tid >> 2) & 3, r = tid & 3;
      float s = 0.f, q = 0.f;
#pragma unroll
      for (int w2 = 0; w2 < 4; ++w2) { s += redS[w2][ct][lg2][r]; q += redQ[w2][ct][lg2][r]; }
      int c = co0 + ct * 16 + lg2 * 4 + r;
      long slot = (long)c * NB + blkLin;
      part2[slot * 2] = s; part2[slot * 2 + 1] = q;
    }
  }
}

// ---------------- stats reduce: part2 -> scale/shift ----------------
__global__ void bn_stats2b(const float* __restrict__ part2, const float* __restrict__ g,
                           const float* __restrict__ b, float* __restrict__ sc,
                           float* __restrict__ sh, int NB, float inv_cnt){
  int c = blockIdx.x, tid = threadIdx.x;
  float s = 0.f, q = 0.f;
  for (int i = tid; i < NB; i += TPB) {
    s += part2[((long)c * NB + i) * 2];
    q += part2[((long)c * NB + i) * 2 + 1];
  }
  __shared__ float ss[TPB], qq[TPB];
  ss[tid] = s; qq[tid] = q;
  __syncthreads();
  for (int off = TPB / 2; off > 0; off >>= 1) {
    if (tid < off) { ss[tid] += ss[tid + off]; qq[tid] += qq[tid + off]; }
    __syncthreads();
  }
  if (tid == 0) {
    float m = ss[0] * inv_cnt, v = qq[0] * inv_cnt - m * m;
    float rs = rsqrtf(v + 1e-5f) * g[c];
    sc[c] = rs;
    sh[c] = b[c] - m * rs;
  }
}

// ---------------- BN apply + ReLU pass (for s1, s2 only) ----------------
__global__ void bn_relu_cl(unsigned short* __restrict__ x, const float* __restrict__ sc,
                           const float* __restrict__ sh, int C, long tot8){
  long i8 = (long)blockIdx.x * TPB + threadIdx.x;
  if (i8 >= tot8) return;
  long e = i8 * 8;
  int c0 = (int)(e & (C - 1));
  ushort8 v = *(ushort8*)(x + e);
  *(ushort8*)(x + e) = bnApply8(v, sc, sh, c0);
}

extern "C" void kernel_launch(void* const* d_in, const int* in_sizes, int n_in,
                              void* d_out, int out_size, void* d_ws, size_t ws_size,
                              hipStream_t stream) {
  const float* x    = (const float*)d_in[0];
  const float* w0   = (const float*)d_in[1];
  const float* g0   = (const float*)d_in[2];
  const float* b0   = (const float*)d_in[3];
  const float* w1   = (const float*)d_in[4];
  const float* g1   = (const float*)d_in[5];
  const float* b1   = (const float*)d_in[6];
  const float* w2   = (const float*)d_in[7];
  const float* g2   = (const float*)d_in[8];
  const float* b2   = (const float*)d_in[9];
  const float* wt2r = (const float*)d_in[10];
  const float* g2r  = (const float*)d_in[11];
  const float* b2r  = (const float*)d_in[12];
  const float* wt1r = (const float*)d_in[13];
  const float* g1r  = (const float*)d_in[14];
  const float* b1r  = (const float*)d_in[15];
  const float* wt0r = (const float*)d_in[16];
  const float* wt2c = (const float*)d_in[17];
  const float* g2c  = (const float*)d_in[18];
  const float* b2c  = (const float*)d_in[19];
  const float* wt1c = (const float*)d_in[20];
  const float* g1c  = (const float*)d_in[21];
  const float* b1c  = (const float*)d_in[22];
  const float* wt0c = (const float*)d_in[23];

  const int N = 2;
  const long sp64 = 262144, sp32 = 32768, sp16 = 4096;

  // ---- workspace (ushort units), all activations NDHWC bf16 ----
  unsigned short* W = (unsigned short*)d_ws;
  unsigned short* s1   = W;                       // [2*sp64][32]
  unsigned short* s2   = s1  + 16777216;          // [2*sp32][64]
  unsigned short* s4   = s2  + 4194304;           // [2*sp16][128]
  unsigned short* r32  = s4  + 1048576;           // [2*sp32][64]
  unsigned short* c32  = r32 + 4194304;           // [2*sp32][64]
  unsigned short* r64  = c32 + 4194304;           // [2*sp64][32]
  unsigned short* xt   = r64;                     // alias (dead after conv0)
  unsigned short* c64  = r64 + 16777216;          // [2*sp64][64]
  unsigned short* wb0p = c64 + 33554432;          // 14*32*32
  unsigned short* wb1  = wb0p + 14336;            // 27*64*32
  unsigned short* wb2  = wb1  + 55296;            // 27*128*64
  unsigned short* wb2r = wb2  + 221184;           // 27*64*128
  unsigned short* wb2c = wb2r + 221184;
  unsigned short* wb1r = wb2c + 221184;           // 27*32*64
  unsigned short* wb1c = wb1r + 55296;            // 27*64*128
  unsigned short* wbrec= wb1c + 221184;           // 27*16*32
  unsigned short* wbcl = wbrec+ 13824;            // 27*16*96
  float* part2  = (float*)(wbcl + 41472);         // 131072 f32
  float* part2b = part2 + 131072;                 // 16384 f32
  float* bsc  = part2b + 16384;                   // shared (s1, s2)
  float* bsh  = bsc + 128;
  float* sc_s4  = bsh  + 128; float* sh_s4  = sc_s4  + 128;
  float* sc_r32 = sh_s4 + 128; float* sh_r32 = sc_r32 + 128;
  float* sc_c32 = sh_r32+ 128; float* sh_c32 = sc_c32 + 128;
  float* sc_r64 = sh_c32+ 128; float* sh_r64 = sc_r64 + 128;
  float* sc_c64 = sh_r64+ 128; float* sh_c64 = sc_c64 + 128;

  float* out_cl  = (float*)d_out;                 // [2][2][64^3] NCDHW
  float* out_rec = (float*)d_out + 2L * 2 * sp64; // [2][16][64^3]

  // ---- merged weight repack + x transpose ----
  rp_all<<<cdiv_l(1064960, TPB), TPB, 0, stream>>>(
      w0, w1, w2, wt2r, wt2c, wt1r, wt1c, wt0r, wt0c,
      wb0p, wb1, wb2, wb2r, wb2c, wb1r, wb1c, wbrec, wbcl);
  xpose_k<<<2048, TPB, 0, stream>>>(x, xt);

  auto gx0 = [&](int G){ return (unsigned)(N * (G >> 1) * (G >> 3) * (G >> 4)); };
  auto gx  = [&](int G){ return (unsigned)(N * (G >> 2) * (G >> 2) * (G >> 4)); };

  // ---- encoder ----
  // conv0 -> s1 (+ fused stats, NB=2048)
  mconv<0, 2, true, false, true><<<dim3(gx0(64), 1), TPB, 0, stream>>>(
      xt, 16, nullptr, 0, nullptr, nullptr, wb0p, s1, part2, (int)gx0(64), N, 32, 32, 32, 64);
  bn_stats2b<<<32, TPB, 0, stream>>>(part2, g0, b0, bsc, bsh, (int)gx0(64), 1.f / (float)(2 * sp64));
  bn_relu_cl<<<cdiv_l(2 * sp64 * 32 / 8, TPB), TPB, 0, stream>>>(s1, bsc, bsh, 32, 2 * sp64 * 32 / 8);

  // conv1 -> s2 (+ stats, NB=gx(32))
  mconv<2, 2, false, false, true><<<dim3(gx(32), 2), TPB, 0, stream>>>(
      s1, 32, nullptr, 0, nullptr, nullptr, wb1, s2, part2, (int)gx(32), N, 64, 64, 32, 32);
  bn_stats2b<<<64, TPB, 0, stream>>>(part2, g1, b1, bsc, bsh, (int)gx(32), 1.f / (float)(2 * sp32));
  bn_relu_cl<<<cdiv_l(2 * sp32 * 64 / 8, TPB), TPB, 0, stream>>>(s2, bsc, bsh, 64, 2 * sp32 * 64 / 8);

  // conv2 -> s4 (+ stats, NB=gx(16))
  mconv<2, 1, false, false, true><<<dim3(gx(16), 8), TPB, 0, stream>>>(
      s2, 64, nullptr, 0, nullptr, nullptr, wb2, s4, part2, (int)gx(16), N, 128, 128, 64, 16);
  bn_stats2b<<<128, TPB, 0, stream>>>(part2, g2, b2, sc_s4, sh_s4, (int)gx(16), 1.f / (float)(2 * sp16));

  // ---- level-2 dual tconv (s4 staged once) -> r32, c32 (+ both stats) ----
  tconv_dual<<<dim3(gx(16), 2, 4), TPB, 0, stream>>>(
      s4, 128, sc_s4, sh_s4, wb2r, wb2c, r32, c32, part2, part2b, (int)gx(16) * 4,
      N, 64, 64, 128, 16);
  bn_stats2b<<<64, TPB, 0, stream>>>(part2, g2r, b2r, sc_r32, sh_r32, (int)gx(16) * 4, 1.f / (float)(2 * sp32));
  bn_stats2b<<<64, TPB, 0, stream>>>(part2b, g2c, b2c, sc_c32, sh_c32, (int)gx(16) * 4, 1.f / (float)(2 * sp32));

  // ---- level-1 tconvs (32 -> 64), quadrants (+ stats) ----
  tconv_quad<2, true><<<dim3(gx(32), 1, 4), TPB, 0, stream>>>(
      r32, 64, nullptr, 0, sc_r32, sh_r32, wb1r, r64, part2, (int)gx(32) * 4, N, 32, 32, 64, 32);
  bn_stats2b<<<32, TPB, 0, stream>>>(part2, g1r, b1r, sc_r64, sh_r64, (int)gx(32) * 4, 1.f / (float)(2 * sp64));
  tconv_quad<4, true><<<dim3(gx(32), 1, 4), TPB, 0, stream>>>(
      c32, 64, s2, 64, sc_c32, sh_c32, wb1c, c64, part2, (int)gx(32) * 4, N, 64, 64, 128, 32);
  bn_stats2b<<<64, TPB, 0, stream>>>(part2, g1c, b1c, sc_c64, sh_c64, (int)gx(32) * 4, 1.f / (float)(2 * sp64));

  // ---- level-0 stride-1 convs (no BN on output), fused BN on inputs ----
  mconv<0, 1, false, true, false><<<dim3(gx0(64), 1), TPB, 0, stream>>>(
      r64, 32, nullptr, 0, sc_r64, sh_r64, wbrec, out_rec, nullptr, 0, N, 16, 16, 32, 64);
  mconv<0, 1, false, true, false><<<dim3(gx0(64), 1), TPB, 0, stream>>>(
      c64, 64, s1, 32, sc_c64, sh_c64, wbcl, out_cl, nullptr, 0, N, 2, 16, 96, 64);
}

// Round 17
// 535.061 us; speedup vs baseline: 1.1233x; 1.0559x over previous
//
#include <hip/hip_runtime.h>
#include <hip/hip_bf16.h>

// ---------------------------------------------------------------------------
// UNet3D dense forward, round 17: R14/R16 compute + launch coalescing.
//  - final_two: rec0+cl0 merged into one dispatch (blockIdx.z param select).
//  - bn_stats2_pair: paired stats reductions (after dual-tconv and after
//    level-1 tconvs; tconv1c now writes part2b).
//  - prep_k: weight repack + x transpose in one dispatch.
//  - 15 dispatches total.
// ---------------------------------------------------------------------------

using bf16 = __hip_bfloat16;
using ushort4v = __attribute__((ext_vector_type(4))) unsigned short;
using ushort8  = __attribute__((ext_vector_type(8))) unsigned short;
using short8   = __attribute__((ext_vector_type(8))) short;
using f32x4    = __attribute__((ext_vector_type(4))) float;
using float4v  = __attribute__((ext_vector_type(4))) float;

#define TPB 256

static inline int cdiv_l(long a, int b){ return (int)((a + b - 1) / b); }

__device__ __forceinline__ float b2f(unsigned short u){
  union { unsigned int i; float f; } v; v.i = ((unsigned int)u) << 16; return v.f;
}
__device__ __forceinline__ unsigned short f2b(float f){
  union { bf16 h; unsigned short u; } v; v.h = __float2bfloat16(f); return v.u;
}
__device__ __forceinline__ ushort8 bnApply8(ushort8 v, const float* sc, const float* sh, int c){
  float4v s0 = *(const float4v*)(sc + c), s1v = *(const float4v*)(sc + c + 4);
  float4v h0 = *(const float4v*)(sh + c), h1v = *(const float4v*)(sh + c + 4);
  ushort8 r;
#pragma unroll
  for (int j = 0; j < 4; ++j){ float y = b2f(v[j]) * s0[j] + h0[j]; r[j] = f2b(y > 0.f ? y : 0.f); }
#pragma unroll
  for (int j = 0; j < 4; ++j){ float y = b2f(v[j+4]) * s1v[j] + h1v[j]; r[j+4] = f2b(y > 0.f ? y : 0.f); }
  return r;
}

// ---------------- prep: x transpose (blocks 0..2047) + weight repack ----------
__global__ void prep_k(const float* __restrict__ x, unsigned short* __restrict__ xt,
                       const float* __restrict__ w0, const float* __restrict__ w1,
                       const float* __restrict__ w2, const float* __restrict__ wt2r,
                       const float* __restrict__ wt2c, const float* __restrict__ wt1r,
                       const float* __restrict__ wt1c, const float* __restrict__ wt0r,
                       const float* __restrict__ wt0c,
                       unsigned short* __restrict__ wb0p, unsigned short* __restrict__ wb1,
                       unsigned short* __restrict__ wb2, unsigned short* __restrict__ wb2r,
                       unsigned short* __restrict__ wb2c, unsigned short* __restrict__ wb1r,
                       unsigned short* __restrict__ wb1c, unsigned short* __restrict__ wbrec,
                       unsigned short* __restrict__ wbcl){
  __shared__ float l[16][257];
  if (blockIdx.x < 2048) {
    int t = threadIdx.x;
    long p0 = (long)blockIdx.x * 256;
    int n = (int)(p0 >> 18);
    long off = p0 & 262143;
    const float* xb = x + ((long)n * 16) * 262144 + off;
#pragma unroll
    for (int c = 0; c < 16; ++c) l[c][t] = xb[(long)c * 262144 + t];
    __syncthreads();
    ushort8 u0, u1;
#pragma unroll
    for (int k = 0; k < 8; ++k){ u0[k] = f2b(l[k][t]); u1[k] = f2b(l[k + 8][t]); }
    unsigned short* o = xt + (p0 + t) * 16;
    *(ushort8*)o = u0; *(ushort8*)(o + 8) = u1;
    return;
  }
  int idx = (blockIdx.x - 2048) * TPB + threadIdx.x;
  auto enc = [](const float* w, unsigned short* d, int i, int Cin, int Cout){
    int ci = i % Cin; int t = i / Cin; int co = t % Cout; int tap = t / Cout;
    d[i] = f2b(w[((long)co * Cin + ci) * 27 + tap]);
  };
  auto dec = [](const float* w, unsigned short* d, int i, int Cin, int Cout, int CIP, int COP){
    int ci = i % CIP; int t = i / CIP; int co = t % COP; int tap = t / COP;
    float v = (ci < Cin && co < Cout) ? w[((long)tap * Cin + ci) * Cout + co] : 0.f;
    d[i] = f2b(v);
  };
  if (idx < 14336) {
    int i = idx;
    int k = i & 31; int t = i >> 5; int co = t & 31; int pp = t >> 5;
    int tap = pp * 2 + (k >> 4); int ci = k & 15;
    float v = (tap < 27) ? w0[((long)co * 16 + ci) * 27 + tap] : 0.f;
    wb0p[i] = f2b(v);
  }
  else if (idx <   69632) enc(w1,  wb1,  idx - 14336,  32, 64);
  else if (idx <  290816) enc(w2,  wb2,  idx - 69632,  64, 128);
  else if (idx <  512000) dec(wt2r, wb2r, idx - 290816, 128, 64, 128, 64);
  else if (idx <  733184) dec(wt2c, wb2c, idx - 512000, 128, 64, 128, 64);
  else if (idx <  788480) dec(wt1r, wb1r, idx - 733184,  64, 32,  64, 32);
  else if (idx < 1009664) dec(wt1c, wb1c, idx - 788480, 128, 64, 128, 64);
  else if (idx < 1023488) dec(wt0r, wbrec, idx - 1009664, 32, 16,  32, 16);
  else if (idx < 1064960) dec(wt0c, wbcl, idx - 1023488, 96,  2,  96, 16);
}

// ---------------- quadrant stride-2 tconv, dbuf LDS, optional fused stats ----
template <int CO_TILES, bool STATS>
__global__ __launch_bounds__(TPB, 2) void tconv_quad(
    const unsigned short* __restrict__ inA, int CA,
    const unsigned short* __restrict__ inB, int CB,
    const float* __restrict__ scA, const float* __restrict__ shA,
    const unsigned short* __restrict__ wb,
    unsigned short* __restrict__ out,
    float* __restrict__ part2, int NB,
    int N, int Cout, int COP, int CIP, int G) {
  __shared__ unsigned short xs[2][4 * 432 * 8];
  const int tid = threadIdx.x, wv = tid >> 6, l = tid & 63, l15 = l & 15, lg = l >> 4;
  int ntW = G >> 4, ntH = G >> 2, ntD = G >> 2;
  int bx = blockIdx.x;
  const int blkLin = blockIdx.x * 4 + blockIdx.z;
  int w0 = (bx % ntW) << 4; bx /= ntW;
  int h0 = (bx % ntH) << 2; bx /= ntH;
  int d0 = (bx % ntD) << 2; int n = bx / ntD;
  const int co0 = blockIdx.y * (16 * CO_TILES);
  const int quad = blockIdx.z;
  const int pd = (quad >> 1) & 1, ph = quad & 1;
  const long spin = (long)G * G * G;

  int nkd, kd_[2], dd_[2], nkh, kh_[2], dh_[2];
  if (pd){ nkd=1; kd_[0]=1; dd_[0]=0; } else { nkd=2; kd_[0]=0; dd_[0]=-1; kd_[1]=2; dd_[1]=0; }
  if (ph){ nkh=1; kh_[0]=1; dh_[0]=0; } else { nkh=2; kh_[0]=0; dh_[0]=-1; kh_[1]=2; dh_[1]=0; }

  f32x4 acc[CO_TILES][4][2];
#pragma unroll
  for (int ct = 0; ct < CO_TILES; ++ct)
#pragma unroll
    for (int j = 0; j < 4; ++j)
#pragma unroll
      for (int p = 0; p < 2; ++p) acc[ct][j][p] = (f32x4){0.f, 0.f, 0.f, 0.f};

  auto stage = [&](int ch, int buf) {
    int c0 = ch << 5;
    const unsigned short* src; int Cs, cl_; bool useBN;
    if (c0 < CA){ src = inA; Cs = CA; cl_ = c0; useBN = (scA != nullptr); }
    else        { src = inB; Cs = CB; cl_ = c0 - CA; useBN = false; }
    const unsigned short* sb = src + (long)n * Cs * spin;
    unsigned short* xb = &xs[buf][0];
    for (int idx = tid; idx < 4 * 425; idx += TPB) {
      int q = idx / 425, pt = idx - q * 425;
      int zw = pt % 17; int zt = pt / 17; int zh = zt % 5; int zd = zt / 5;
      int gd = d0 + zd - 1, gh = h0 + zh - 1, gw = w0 + zw - 1;
      ushort8 v = (ushort8){0,0,0,0,0,0,0,0};
      if ((unsigned)gd < (unsigned)G && (unsigned)gh < (unsigned)G && (unsigned)gw < (unsigned)G) {
        v = *(const ushort8*)(sb + (((long)gd * G + gh) * G + gw) * Cs + cl_ + q * 8);
        if (useBN) v = bnApply8(v, scA, shA, cl_ + q * 8);
      }
      *(ushort8*)(xb + (q * 432 + pt) * 8) = v;
    }
  };

  const int nch = CIP >> 5;
  stage(0, 0);
  __syncthreads();
#pragma unroll 1
  for (int ch = 0; ch < nch; ++ch) {
    int cur = ch & 1;
    int c0 = ch << 5;
    if (ch + 1 < nch) stage(ch + 1, cur ^ 1);
    const unsigned short* xr = &xs[cur][0];
#pragma unroll 1
    for (int a = 0; a < nkd; ++a) {
      int zd = wv + 1 + dd_[a];
#pragma unroll 1
      for (int b = 0; b < nkh; ++b) {
        int tapb = (kd_[a] * 3 + kh_[b]) * 3;
        const unsigned short* ap = wb + ((long)tapb * COP + co0 + l15) * CIP + c0 + lg * 8;
        long tstride = (long)COP * CIP;
        short8 Ak0[CO_TILES], Ak1[CO_TILES], Ak2[CO_TILES];
#pragma unroll
        for (int ct = 0; ct < CO_TILES; ++ct) {
          Ak0[ct] = *(const short8*)(ap + ct * 16 * CIP);
          Ak1[ct] = *(const short8*)(ap + tstride + ct * 16 * CIP);
          Ak2[ct] = *(const short8*)(ap + 2 * tstride + ct * 16 * CIP);
        }
        int zh0 = 1 + dh_[b];
#pragma unroll
        for (int j = 0; j < 4; ++j) {
          int basept = (zd * 5 + (j + zh0)) * 17 + l15;
          short8 Bm = *(const short8*)(xr + (lg * 432 + basept) * 8);
          short8 B0 = *(const short8*)(xr + (lg * 432 + basept + 1) * 8);
#pragma unroll
          for (int ct = 0; ct < CO_TILES; ++ct) {
            acc[ct][j][0] = __builtin_amdgcn_mfma_f32_16x16x32_bf16(Ak0[ct], Bm, acc[ct][j][0], 0, 0, 0);
            acc[ct][j][0] = __builtin_amdgcn_mfma_f32_16x16x32_bf16(Ak2[ct], B0, acc[ct][j][0], 0, 0, 0);
            acc[ct][j][1] = __builtin_amdgcn_mfma_f32_16x16x32_bf16(Ak1[ct], B0, acc[ct][j][1], 0, 0, 0);
          }
        }
      }
    }
    __syncthreads();
  }

  int Gout = 2 * G; long spo = (long)Gout * Gout * Gout;
  int od = 2 * (d0 + wv) + pd;
#pragma unroll
  for (int j = 0; j < 4; ++j) {
    int oh = 2 * (h0 + j) + ph;
#pragma unroll
    for (int p = 0; p < 2; ++p) {
      int ow = 2 * (w0 + l15) + p;
      long pt = ((long)od * Gout + oh) * Gout + ow;
#pragma unroll
      for (int ct = 0; ct < CO_TILES; ++ct) {
        ushort4v pk;
#pragma unroll
        for (int r = 0; r < 4; ++r) pk[r] = f2b(acc[ct][j][p][r]);
        *(ushort4v*)(out + ((long)n * spo + pt) * Cout + co0 + ct * 16 + lg * 4) = pk;
      }
    }
  }

  if constexpr (STATS) {
    __shared__ float redS[4][CO_TILES][4][4];
    __shared__ float redQ[4][CO_TILES][4][4];
#pragma unroll
    for (int ct = 0; ct < CO_TILES; ++ct)
#pragma unroll
      for (int r = 0; r < 4; ++r) {
        float s = 0.f, q = 0.f;
#pragma unroll
        for (int j = 0; j < 4; ++j)
#pragma unroll
          for (int p = 0; p < 2; ++p) { float a = acc[ct][j][p][r]; s += a; q += a * a; }
#pragma unroll
        for (int m = 1; m < 16; m <<= 1) { s += __shfl_xor(s, m); q += __shfl_xor(q, m); }
        if (l15 == 0) { redS[wv][ct][lg][r] = s; redQ[wv][ct][lg][r] = q; }
      }
    __syncthreads();
    if (tid < CO_TILES * 16) {
      int ct = tid >> 4, lg2 = (tid >> 2) & 3, r = tid & 3;
      float s = 0.f, q = 0.f;
#pragma unroll
      for (int w2 = 0; w2 < 4; ++w2) { s += redS[w2][ct][lg2][r]; q += redQ[w2][ct][lg2][r]; }
      int c = co0 + ct * 16 + lg2 * 4 + r;
      long slot = (long)c * NB + blkLin;
      part2[slot * 2] = s; part2[slot * 2 + 1] = q;
    }
  }
}

// ---------------- dual-head quadrant tconv2 (shared s4 staging) ------------
__global__ __launch_bounds__(TPB) void tconv_dual(
    const unsigned short* __restrict__ in, int CI,
    const float* __restrict__ scA, const float* __restrict__ shA,
    const unsigned short* __restrict__ wbA, const unsigned short* __restrict__ wbB,
    unsigned short* __restrict__ outA, unsigned short* __restrict__ outB,
    float* __restrict__ p2A, float* __restrict__ p2B, int NB,
    int N, int Cout, int COP, int CIP, int G) {
  const int CT = 2;
  __shared__ unsigned short xs[4 * 432 * 8];
  const int tid = threadIdx.x, wv = tid >> 6, l = tid & 63, l15 = l & 15, lg = l >> 4;
  int ntW = G >> 4, ntH = G >> 2, ntD = G >> 2;
  int bx = blockIdx.x;
  const int blkLin = blockIdx.x * 4 + blockIdx.z;
  int w0 = (bx % ntW) << 4; bx /= ntW;
  int h0 = (bx % ntH) << 2; bx /= ntH;
  int d0 = (bx % ntD) << 2; int n = bx / ntD;
  const int co0 = blockIdx.y * (16 * CT);
  const int quad = blockIdx.z;
  const int pd = (quad >> 1) & 1, ph = quad & 1;
  const long spin = (long)G * G * G;

  int nkd, kd_[2], dd_[2], nkh, kh_[2], dh_[2];
  if (pd){ nkd=1; kd_[0]=1; dd_[0]=0; } else { nkd=2; kd_[0]=0; dd_[0]=-1; kd_[1]=2; dd_[1]=0; }
  if (ph){ nkh=1; kh_[0]=1; dh_[0]=0; } else { nkh=2; kh_[0]=0; dh_[0]=-1; kh_[1]=2; dh_[1]=0; }

  f32x4 acc[2][CT][4][2];
#pragma unroll
  for (int h = 0; h < 2; ++h)
#pragma unroll
    for (int ct = 0; ct < CT; ++ct)
#pragma unroll
      for (int j = 0; j < 4; ++j)
#pragma unroll
        for (int p = 0; p < 2; ++p) acc[h][ct][j][p] = (f32x4){0.f, 0.f, 0.f, 0.f};

  const int nch = CIP >> 5;
#pragma unroll 1
  for (int ch = 0; ch < nch; ++ch) {
    int c0 = ch << 5;
    const unsigned short* sb = in + (long)n * CI * spin;
    __syncthreads();
    for (int idx = tid; idx < 4 * 425; idx += TPB) {
      int q = idx / 425, pt = idx - q * 425;
      int zw = pt % 17; int zt = pt / 17; int zh = zt % 5; int zd = zt / 5;
      int gd = d0 + zd - 1, gh = h0 + zh - 1, gw = w0 + zw - 1;
      ushort8 v = (ushort8){0,0,0,0,0,0,0,0};
      if ((unsigned)gd < (unsigned)G && (unsigned)gh < (unsigned)G && (unsigned)gw < (unsigned)G) {
        v = *(const ushort8*)(sb + (((long)gd * G + gh) * G + gw) * CI + c0 + q * 8);
        v = bnApply8(v, scA, shA, c0 + q * 8);
      }
      *(ushort8*)(xs + (q * 432 + pt) * 8) = v;
    }
    __syncthreads();
#pragma unroll 1
    for (int a = 0; a < nkd; ++a) {
      int zd = wv + 1 + dd_[a];
#pragma unroll 1
      for (int b = 0; b < nkh; ++b) {
        int tapb = (kd_[a] * 3 + kh_[b]) * 3;
        long tstride = (long)COP * CIP;
        long abase = ((long)tapb * COP + co0 + l15) * CIP + c0 + lg * 8;
        int zh0 = 1 + dh_[b];
#pragma unroll
        for (int h = 0; h < 2; ++h) {
          const unsigned short* ap = (h == 0 ? wbA : wbB) + abase;
          short8 Ak0[CT], Ak1[CT], Ak2[CT];
#pragma unroll
          for (int ct = 0; ct < CT; ++ct) {
            Ak0[ct] = *(const short8*)(ap + ct * 16 * CIP);
            Ak1[ct] = *(const short8*)(ap + tstride + ct * 16 * CIP);
            Ak2[ct] = *(const short8*)(ap + 2 * tstride + ct * 16 * CIP);
          }
#pragma unroll
          for (int j = 0; j < 4; ++j) {
            int basept = (zd * 5 + (j + zh0)) * 17 + l15;
            short8 Bm = *(const short8*)(xs + (lg * 432 + basept) * 8);
            short8 B0 = *(const short8*)(xs + (lg * 432 + basept + 1) * 8);
#pragma unroll
            for (int ct = 0; ct < CT; ++ct) {
              acc[h][ct][j][0] = __builtin_amdgcn_mfma_f32_16x16x32_bf16(Ak0[ct], Bm, acc[h][ct][j][0], 0, 0, 0);
              acc[h][ct][j][0] = __builtin_amdgcn_mfma_f32_16x16x32_bf16(Ak2[ct], B0, acc[h][ct][j][0], 0, 0, 0);
              acc[h][ct][j][1] = __builtin_amdgcn_mfma_f32_16x16x32_bf16(Ak1[ct], B0, acc[h][ct][j][1], 0, 0, 0);
            }
          }
        }
      }
    }
  }

  int Gout = 2 * G; long spo = (long)Gout * Gout * Gout;
  int od = 2 * (d0 + wv) + pd;
#pragma unroll
  for (int j = 0; j < 4; ++j) {
    int oh = 2 * (h0 + j) + ph;
#pragma unroll
    for (int p = 0; p < 2; ++p) {
      int ow = 2 * (w0 + l15) + p;
      long pt = ((long)od * Gout + oh) * Gout + ow;
#pragma unroll
      for (int h = 0; h < 2; ++h) {
        unsigned short* o = h == 0 ? outA : outB;
#pragma unroll
        for (int ct = 0; ct < CT; ++ct) {
          ushort4v pk;
#pragma unroll
          for (int r = 0; r < 4; ++r) pk[r] = f2b(acc[h][ct][j][p][r]);
          *(ushort4v*)(o + ((long)n * spo + pt) * Cout + co0 + ct * 16 + lg * 4) = pk;
        }
      }
    }
  }

  __shared__ float redS[4][CT][4][4];
  __shared__ float redQ[4][CT][4][4];
#pragma unroll 1
  for (int h = 0; h < 2; ++h) {
    __syncthreads();
#pragma unroll
    for (int ct = 0; ct < CT; ++ct)
#pragma unroll
      for (int r = 0; r < 4; ++r) {
        float s = 0.f, q = 0.f;
#pragma unroll
        for (int j = 0; j < 4; ++j)
#pragma unroll
          for (int p = 0; p < 2; ++p) { float a = acc[h][ct][j][p][r]; s += a; q += a * a; }
#pragma unroll
        for (int m = 1; m < 16; m <<= 1) { s += __shfl_xor(s, m); q += __shfl_xor(q, m); }
        if (l15 == 0) { redS[wv][ct][lg][r] = s; redQ[wv][ct][lg][r] = q; }
      }
    __syncthreads();
    if (tid < CT * 16) {
      int ct = tid >> 4, lg2 = (tid >> 2) & 3, r = tid & 3;
      float s = 0.f, q = 0.f;
#pragma unroll
      for (int w2 = 0; w2 < 4; ++w2) { s += redS[w2][ct][lg2][r]; q += redQ[w2][ct][lg2][r]; }
      int c = co0 + ct * 16 + lg2 * 4 + r;
      long slot = (long)c * NB + blkLin;
      float* p2 = h == 0 ? p2A : p2B;
      p2[slot * 2] = s; p2[slot * 2 + 1] = q;
    }
  }
}

// ---------------- unified NDHWC MFMA conv (PAIRED conv0 / V2 stride-2) -----
template <int VARIANT, int CO_TILES, bool PAIRED, bool FOUT, bool STATS>
__global__ __launch_bounds__(TPB) void mconv(
    const unsigned short* __restrict__ inA, int CA,
    const unsigned short* __restrict__ inB, int CB,
    const float* __restrict__ scA, const float* __restrict__ shA,
    const unsigned short* __restrict__ wb,
    void* __restrict__ outv,
    float* __restrict__ part2, int NB,
    int N, int Cout, int COP, int CIP, int G) {
  const int tid = threadIdx.x, wv = tid >> 6, l = tid & 63, l15 = l & 15, lg = l >> 4;
  int bx = blockIdx.x;
  const int blkLin = blockIdx.x;
  int w0, h0, d0, n;
  int wvd = wv & 1, jh = wv >> 1, jbase = jh * 4;
  if constexpr (VARIANT == 0) {
    int ntW = G >> 4, ntH = G >> 3, ntD = G >> 1;
    w0 = (bx % ntW) << 4; bx /= ntW;
    h0 = (bx % ntH) << 3; bx /= ntH;
    d0 = (bx % ntD) << 1; n = bx / ntD;
  } else {
    int ntW = G >> 4, ntH = G >> 2, ntD = G >> 2;
    w0 = (bx % ntW) << 4; bx /= ntW;
    h0 = (bx % ntH) << 2; bx /= ntH;
    d0 = (bx % ntD) << 2; n = bx / ntD;
  }
  const int co0 = blockIdx.y * (16 * CO_TILES);
  const int Gin = (VARIANT == 2) ? 2 * G : G;
  const long spin = (long)Gin * Gin * Gin;

  f32x4 acc[CO_TILES][4];
#pragma unroll
  for (int ct = 0; ct < CO_TILES; ++ct)
#pragma unroll
    for (int j = 0; j < 4; ++j) acc[ct][j] = (f32x4){0.f, 0.f, 0.f, 0.f};

  if constexpr (PAIRED) {
    __shared__ unsigned short xs[2 * 728 * 8];
    const unsigned short* src = inA + (long)n * 16 * spin;
    for (int idx = tid; idx < 2 * 720; idx += TPB) {
      int q = idx / 720, pt = idx - q * 720;
      int zw = pt % 18; int zt = pt / 18; int zh = zt % 10; int zd = zt / 10;
      int gd = d0 + zd - 1, gh = h0 + zh - 1, gw = w0 + zw - 1;
      ushort8 v = (ushort8){0,0,0,0,0,0,0,0};
      if ((unsigned)gd < (unsigned)G && (unsigned)gh < (unsigned)G && (unsigned)gw < (unsigned)G)
        v = *(const ushort8*)(src + (((long)gd * G + gh) * G + gw) * 16 + q * 8);
      *(ushort8*)(xs + (q * 728 + pt) * 8) = v;
    }
    __syncthreads();
#pragma unroll 1
    for (int pp = 0; pp < 14; ++pp) {
      short8 A0 = *(const short8*)(wb + ((pp * 32 + l15) * 32) + lg * 8);
      short8 A1 = *(const short8*)(wb + ((pp * 32 + 16 + l15) * 32) + lg * 8);
      int t0 = 2 * pp + (lg >> 1); if (t0 > 26) t0 = 26;
      int dd = t0 / 9 - 1, dh = (t0 / 3) % 3 - 1, dw = t0 % 3 - 1;
      int q = lg & 1;
      int zd = wvd + 1 + dd;
      int base = (q * 728 + (zd * 10 + (1 + dh + jbase)) * 18 + 1 + l15 + dw) * 8;
#pragma unroll
      for (int j = 0; j < 4; ++j) {
        short8 B = *(const short8*)(xs + base + j * (18 * 8));
        acc[0][j] = __builtin_amdgcn_mfma_f32_16x16x32_bf16(A0, B, acc[0][j], 0, 0, 0);
        if (CO_TILES == 2)
          acc[1][j] = __builtin_amdgcn_mfma_f32_16x16x32_bf16(A1, B, acc[1][j], 0, 0, 0);
      }
    }
  } else {
    const int nch = CIP >> 5;
#pragma unroll 1
    for (int ch = 0; ch < nch; ++ch) {
      int c0 = ch << 5;
      const unsigned short* src; int Cs, cl_;
      if (c0 < CA){ src = inA; Cs = CA; cl_ = c0; } else { src = inB; Cs = CB; cl_ = c0 - CA; }
      const unsigned short* sb = src + (long)n * Cs * spin;
#pragma unroll 1
      for (int a = 0; a < 3; ++a) {
        int gd = 2 * (d0 + wv) + a - 1;
        bool vd = (unsigned)gd < (unsigned)Gin;
#pragma unroll 1
        for (int b = 0; b < 3; ++b) {
#pragma unroll
          for (int c = 0; c < 3; ++c) {
            int tap = (a * 3 + b) * 3 + c;
            const unsigned short* ap = wb + ((long)tap * COP + co0 + l15) * CIP + c0 + lg * 8;
            short8 A0 = *(const short8*)ap;
            short8 A1;
            if (CO_TILES == 2) A1 = *(const short8*)(ap + 16 * CIP);
            int gw = 2 * (w0 + l15) + c - 1;
            bool vdw = vd && ((unsigned)gw < (unsigned)Gin);
#pragma unroll
            for (int j = 0; j < 4; ++j) {
              int gh = 2 * (h0 + j) + b - 1;
              short8 B = (short8){0,0,0,0,0,0,0,0};
              if (vdw && (unsigned)gh < (unsigned)Gin)
                B = *(const short8*)(sb + (((long)gd * Gin + gh) * Gin + gw) * Cs + cl_ + lg * 8);
              acc[0][j] = __builtin_amdgcn_mfma_f32_16x16x32_bf16(A0, B, acc[0][j], 0, 0, 0);
              if (CO_TILES == 2)
                acc[1][j] = __builtin_amdgcn_mfma_f32_16x16x32_bf16(A1, B, acc[1][j], 0, 0, 0);
            }
          }
        }
      }
    }
  }

  const long spo = (long)G * G * G;
#pragma unroll
  for (int j = 0; j < 4; ++j) {
    long pt;
    if constexpr (VARIANT == 0)
      pt = ((long)(d0 + wvd) * G + (h0 + jbase + j)) * G + (w0 + l15);
    else
      pt = ((long)(d0 + wv) * G + (h0 + j)) * G + (w0 + l15);
    if constexpr (!FOUT) {
      unsigned short* outp = (unsigned short*)outv;
#pragma unroll
      for (int ct = 0; ct < CO_TILES; ++ct) {
        ushort4v pk;
#pragma unroll
        for (int r = 0; r < 4; ++r) pk[r] = f2b(acc[ct][j][r]);
        *(ushort4v*)(outp + ((long)n * spo + pt) * Cout + co0 + ct * 16 + lg * 4) = pk;
      }
    } else {
      float* outp = (float*)outv;
#pragma unroll
      for (int ct = 0; ct < CO_TILES; ++ct)
#pragma unroll
        for (int r = 0; r < 4; ++r) {
          int co = co0 + ct * 16 + lg * 4 + r;
          if (co < Cout) outp[((long)(n * Cout + co)) * spo + pt] = acc[ct][j][r];
        }
    }
  }

  if constexpr (STATS) {
    __shared__ float redS[4][CO_TILES][4][4];
    __shared__ float redQ[4][CO_TILES][4][4];
#pragma unroll
    for (int ct = 0; ct < CO_TILES; ++ct)
#pragma unroll
      for (int r = 0; r < 4; ++r) {
        float s = 0.f, q = 0.f;
#pragma unroll
        for (int j = 0; j < 4; ++j) { float a = acc[ct][j][r]; s += a; q += a * a; }
#pragma unroll
        for (int m = 1; m < 16; m <<= 1) { s += __shfl_xor(s, m); q += __shfl_xor(q, m); }
        if (l15 == 0) { redS[wv][ct][lg][r] = s; redQ[wv][ct][lg][r] = q; }
      }
    __syncthreads();
    if (tid < CO_TILES * 16) {
      int ct = tid >> 4, lg2 = (tid >> 2) & 3, r = tid & 3;
      float s = 0.f, q = 0.f;
#pragma unroll
      for (int w2 = 0; w2 < 4; ++w2) { s += redS[w2][ct][lg2][r]; q += redQ[w2][ct][lg2][r]; }
      int c = co0 + ct * 16 + lg2 * 4 + r;
      long slot = (long)c * NB + blkLin;
      part2[slot * 2] = s; part2[slot * 2 + 1] = q;
    }
  }
}

// ---------------- merged final stride-1 convs: z=0 rec, z=1 cl -------------
__global__ __launch_bounds__(TPB) void final_two(
    const unsigned short* __restrict__ r64,
    const float* __restrict__ sc_r64, const float* __restrict__ sh_r64,
    const unsigned short* __restrict__ wbrec, float* __restrict__ out_rec,
    const unsigned short* __restrict__ c64, const unsigned short* __restrict__ s1,
    const float* __restrict__ sc_c64, const float* __restrict__ sh_c64,
    const unsigned short* __restrict__ wbcl, float* __restrict__ out_cl,
    int N, int G) {
  const unsigned short* inA; int CA; const unsigned short* inB; int CB;
  const float* scA; const float* shA; const unsigned short* wb;
  float* outp; int Cout, COP, CIP;
  if (blockIdx.z == 0) {
    inA = r64; CA = 32; inB = nullptr; CB = 0; scA = sc_r64; shA = sh_r64;
    wb = wbrec; outp = out_rec; Cout = 16; COP = 16; CIP = 32;
  } else {
    inA = c64; CA = 64; inB = s1; CB = 32; scA = sc_c64; shA = sh_c64;
    wb = wbcl; outp = out_cl; Cout = 2; COP = 16; CIP = 96;
  }
  const int tid = threadIdx.x, wv = tid >> 6, l = tid & 63, l15 = l & 15, lg = l >> 4;
  int bx = blockIdx.x;
  int wvd = wv & 1, jh = wv >> 1, jbase = jh * 4;
  int ntW = G >> 4, ntH = G >> 3, ntD = G >> 1;
  int w0 = (bx % ntW) << 4; bx /= ntW;
  int h0 = (bx % ntH) << 3; bx /= ntH;
  int d0 = (bx % ntD) << 1; int n = bx / ntD;
  const long spin = (long)G * G * G;

  f32x4 acc[4];
#pragma unroll
  for (int j = 0; j < 4; ++j) acc[j] = (f32x4){0.f, 0.f, 0.f, 0.f};

  __shared__ unsigned short xs[4 * 728 * 8];
  const int nch = CIP >> 5;
#pragma unroll 1
  for (int ch = 0; ch < nch; ++ch) {
    int c0 = ch << 5;
    const unsigned short* src; int Cs, cl_; bool useBN;
    if (c0 < CA){ src = inA; Cs = CA; cl_ = c0; useBN = (scA != nullptr); }
    else        { src = inB; Cs = CB; cl_ = c0 - CA; useBN = false; }
    const unsigned short* sb = src + (long)n * Cs * spin;
    __syncthreads();
    for (int idx = tid; idx < 4 * 720; idx += TPB) {
      int q = idx / 720, pt = idx - q * 720;
      int zw = pt % 18; int zt = pt / 18; int zh = zt % 10; int zd = zt / 10;
      int gd = d0 + zd - 1, gh = h0 + zh - 1, gw = w0 + zw - 1;
      ushort8 v = (ushort8){0,0,0,0,0,0,0,0};
      if ((unsigned)gd < (unsigned)G && (unsigned)gh < (unsigned)G && (unsigned)gw < (unsigned)G) {
        v = *(const ushort8*)(sb + (((long)gd * G + gh) * G + gw) * Cs + cl_ + q * 8);
        if (useBN) v = bnApply8(v, scA, shA, cl_ + q * 8);
      }
      *(ushort8*)(xs + (q * 728 + pt) * 8) = v;
    }
    __syncthreads();
#pragma unroll 1
    for (int a = 0; a < 3; ++a) {
      int zd = wvd + a;
      short8 A0[3][3];
#pragma unroll
      for (int b = 0; b < 3; ++b)
#pragma unroll
        for (int c = 0; c < 3; ++c) {
          int tap = (a * 3 + b) * 3 + c;
          A0[b][c] = *(const short8*)(wb + ((long)tap * COP + l15) * CIP + c0 + lg * 8);
        }
#pragma unroll
      for (int sl = 0; sl < 6; ++sl) {
        int sg = jbase + sl;
        int rb = (lg * 728 + (zd * 10 + sg) * 18 + l15) * 8;
        short8 B0 = *(const short8*)(xs + rb);
        short8 B1 = *(const short8*)(xs + rb + 8);
        short8 B2 = *(const short8*)(xs + rb + 16);
#pragma unroll
        for (int b = 0; b < 3; ++b) {
          int j = sl - b;
          if (j >= 0 && j < 4) {
            acc[j] = __builtin_amdgcn_mfma_f32_16x16x32_bf16(A0[b][0], B0, acc[j], 0, 0, 0);
            acc[j] = __builtin_amdgcn_mfma_f32_16x16x32_bf16(A0[b][1], B1, acc[j], 0, 0, 0);
            acc[j] = __builtin_amdgcn_mfma_f32_16x16x32_bf16(A0[b][2], B2, acc[j], 0, 0, 0);
          }
        }
      }
    }
  }

  const long spo = (long)G * G * G;
#pragma unroll
  for (int j = 0; j < 4; ++j) {
    long pt = ((long)(d0 + wvd) * G + (h0 + jbase + j)) * G + (w0 + l15);
#pragma unroll
    for (int r = 0; r < 4; ++r) {
      int co = lg * 4 + r;
      if (co < Cout) outp[((long)(n * Cout + co)) * spo + pt] = acc[j][r];
    }
  }
}

// ---------------- stats reduce: single ----------------
__global__ void bn_stats2b(const float* __restrict__ part2, const float* __restrict__ g,
                           const float* __restrict__ b, float* __restrict__ sc,
                           float* __restrict__ sh, int NB, float inv_cnt){
  int c = blockIdx.x, tid = threadIdx.x;
  float s = 0.f, q = 0.f;
  for (int i = tid; i < NB; i += TPB) {
    s += part2[((long)c * NB + i) * 2];
    q += part2[((long)c * NB + i) * 2 + 1];
  }
  __shared__ float ss[TPB], qq[TPB];
  ss[tid] = s; qq[tid] = q;
  __syncthreads();
  for (int off = TPB / 2; off > 0; off >>= 1) {
    if (tid < off) { ss[tid] += ss[tid + off]; qq[tid] += qq[tid + off]; }
    __syncthreads();
  }
  if (tid == 0) {
    float m = ss[0] * inv_cnt, v = qq[0] * inv_cnt - m * m;
    float rs = rsqrtf(v + 1e-5f) * g[c];
    sc[c] = rs;
    sh[c] = b[c] - m * rs;
  }
}

// ---------------- stats reduce: paired (two tensors, one launch) ----------
__global__ void bn_stats2_pair(
    const float* __restrict__ pA, const float* __restrict__ gA, const float* __restrict__ bA,
    float* __restrict__ scA, float* __restrict__ shA, int CAch,
    const float* __restrict__ pB, const float* __restrict__ gB, const float* __restrict__ bB,
    float* __restrict__ scB, float* __restrict__ shB,
    int NB, float inv_cnt){
  int c = blockIdx.x, tid = threadIdx.x;
  const float* part; const float* g; const float* b; float* sc; float* sh; int cc;
  if (c < CAch) { part = pA; g = gA; b = bA; sc = scA; sh = shA; cc = c; }
  else          { part = pB; g = gB; b = bB; sc = scB; sh = shB; cc = c - CAch; }
  float s = 0.f, q = 0.f;
  for (int i = tid; i < NB; i += TPB) {
    s += part[((long)cc * NB + i) * 2];
    q += part[((long)cc * NB + i) * 2 + 1];
  }
  __shared__ float ss[TPB], qq[TPB];
  ss[tid] = s; qq[tid] = q;
  __syncthreads();
  for (int off = TPB / 2; off > 0; off >>= 1) {
    if (tid < off) { ss[tid] += ss[tid + off]; qq[tid] += qq[tid + off]; }
    __syncthreads();
  }
  if (tid == 0) {
    float m = ss[0] * inv_cnt, v = qq[0] * inv_cnt - m * m;
    float rs = rsqrtf(v + 1e-5f) * g[cc];
    sc[cc] = rs;
    sh[cc] = b[cc] - m * rs;
  }
}

// ---------------- BN apply + ReLU pass (for s1, s2 only) ----------------
__global__ void bn_relu_cl(unsigned short* __restrict__ x, const float* __restrict__ sc,
                           const float* __restrict__ sh, int C, long tot8){
  long i8 = (long)blockIdx.x * TPB + threadIdx.x;
  if (i8 >= tot8) return;
  long e = i8 * 8;
  int c0 = (int)(e & (C - 1));
  ushort8 v = *(ushort8*)(x + e);
  *(ushort8*)(x + e) = bnApply8(v, sc, sh, c0);
}

extern "C" void kernel_launch(void* const* d_in, const int* in_sizes, int n_in,
                              void* d_out, int out_size, void* d_ws, size_t ws_size,
                              hipStream_t stream) {
  const float* x    = (const float*)d_in[0];
  const float* w0   = (const float*)d_in[1];
  const float* g0   = (const float*)d_in[2];
  const float* b0   = (const float*)d_in[3];
  const float* w1   = (const float*)d_in[4];
  const float* g1   = (const float*)d_in[5];
  const float* b1   = (const float*)d_in[6];
  const float* w2   = (const float*)d_in[7];
  const float* g2   = (const float*)d_in[8];
  const float* b2   = (const float*)d_in[9];
  const float* wt2r = (const float*)d_in[10];
  const float* g2r  = (const float*)d_in[11];
  const float* b2r  = (const float*)d_in[12];
  const float* wt1r = (const float*)d_in[13];
  const float* g1r  = (const float*)d_in[14];
  const float* b1r  = (const float*)d_in[15];
  const float* wt0r = (const float*)d_in[16];
  const float* wt2c = (const float*)d_in[17];
  const float* g2c  = (const float*)d_in[18];
  const float* b2c  = (const float*)d_in[19];
  const float* wt1c = (const float*)d_in[20];
  const float* g1c  = (const float*)d_in[21];
  const float* b1c  = (const float*)d_in[22];
  const float* wt0c = (const float*)d_in[23];

  const int N = 2;
  const long sp64 = 262144, sp32 = 32768, sp16 = 4096;

  // ---- workspace (ushort units), all activations NDHWC bf16 ----
  unsigned short* W = (unsigned short*)d_ws;
  unsigned short* s1   = W;                       // [2*sp64][32]
  unsigned short* s2   = s1  + 16777216;          // [2*sp32][64]
  unsigned short* s4   = s2  + 4194304;           // [2*sp16][128]
  unsigned short* r32  = s4  + 1048576;           // [2*sp32][64]
  unsigned short* c32  = r32 + 4194304;           // [2*sp32][64]
  unsigned short* r64  = c32 + 4194304;           // [2*sp64][32]
  unsigned short* xt   = r64;                     // alias (dead after conv0)
  unsigned short* c64  = r64 + 16777216;          // [2*sp64][64]
  unsigned short* wb0p = c64 + 33554432;          // 14*32*32
  unsigned short* wb1  = wb0p + 14336;            // 27*64*32
  unsigned short* wb2  = wb1  + 55296;            // 27*128*64
  unsigned short* wb2r = wb2  + 221184;           // 27*64*128
  unsigned short* wb2c = wb2r + 221184;
  unsigned short* wb1r = wb2c + 221184;           // 27*32*64
  unsigned short* wb1c = wb1r + 55296;            // 27*64*128
  unsigned short* wbrec= wb1c + 221184;           // 27*16*32
  unsigned short* wbcl = wbrec+ 13824;            // 27*16*96
  float* part2  = (float*)(wbcl + 41472);         // 131072 f32
  float* part2b = part2 + 131072;                 // 131072 f32
  float* bsc  = part2b + 131072;                  // shared (s1, s2)
  float* bsh  = bsc + 128;
  float* sc_s4  = bsh  + 128; float* sh_s4  = sc_s4  + 128;
  float* sc_r32 = sh_s4 + 128; float* sh_r32 = sc_r32 + 128;
  float* sc_c32 = sh_r32+ 128; float* sh_c32 = sc_c32 + 128;
  float* sc_r64 = sh_c32+ 128; float* sh_r64 = sc_r64 + 128;
  float* sc_c64 = sh_r64+ 128; float* sh_c64 = sc_c64 + 128;

  float* out_cl  = (float*)d_out;                 // [2][2][64^3] NCDHW
  float* out_rec = (float*)d_out + 2L * 2 * sp64; // [2][16][64^3]

  // ---- prep: weight repack + x transpose (one dispatch) ----
  prep_k<<<2048 + cdiv_l(1064960, TPB), TPB, 0, stream>>>(
      x, xt, w0, w1, w2, wt2r, wt2c, wt1r, wt1c, wt0r, wt0c,
      wb0p, wb1, wb2, wb2r, wb2c, wb1r, wb1c, wbrec, wbcl);

  auto gx0 = [&](int G){ return (unsigned)(N * (G >> 1) * (G >> 3) * (G >> 4)); };
  auto gx  = [&](int G){ return (unsigned)(N * (G >> 2) * (G >> 2) * (G >> 4)); };

  // ---- encoder ----
  mconv<0, 2, true, false, true><<<dim3(gx0(64), 1), TPB, 0, stream>>>(
      xt, 16, nullptr, 0, nullptr, nullptr, wb0p, s1, part2, (int)gx0(64), N, 32, 32, 32, 64);
  bn_stats2b<<<32, TPB, 0, stream>>>(part2, g0, b0, bsc, bsh, (int)gx0(64), 1.f / (float)(2 * sp64));
  bn_relu_cl<<<cdiv_l(2 * sp64 * 32 / 8, TPB), TPB, 0, stream>>>(s1, bsc, bsh, 32, 2 * sp64 * 32 / 8);

  mconv<2, 2, false, false, true><<<dim3(gx(32), 2), TPB, 0, stream>>>(
      s1, 32, nullptr, 0, nullptr, nullptr, wb1, s2, part2, (int)gx(32), N, 64, 64, 32, 32);
  bn_stats2b<<<64, TPB, 0, stream>>>(part2, g1, b1, bsc, bsh, (int)gx(32), 1.f / (float)(2 * sp32));
  bn_relu_cl<<<cdiv_l(2 * sp32 * 64 / 8, TPB), TPB, 0, stream>>>(s2, bsc, bsh, 64, 2 * sp32 * 64 / 8);

  mconv<2, 1, false, false, true><<<dim3(gx(16), 8), TPB, 0, stream>>>(
      s2, 64, nullptr, 0, nullptr, nullptr, wb2, s4, part2, (int)gx(16), N, 128, 128, 64, 16);
  bn_stats2b<<<128, TPB, 0, stream>>>(part2, g2, b2, sc_s4, sh_s4, (int)gx(16), 1.f / (float)(2 * sp16));

  // ---- level-2 dual tconv (s4 staged once) -> r32, c32; paired stats ----
  tconv_dual<<<dim3(gx(16), 2, 4), TPB, 0, stream>>>(
      s4, 128, sc_s4, sh_s4, wb2r, wb2c, r32, c32, part2, part2b, (int)gx(16) * 4,
      N, 64, 64, 128, 16);
  bn_stats2_pair<<<128, TPB, 0, stream>>>(
      part2, g2r, b2r, sc_r32, sh_r32, 64,
      part2b, g2c, b2c, sc_c32, sh_c32, (int)gx(16) * 4, 1.f / (float)(2 * sp32));

  // ---- level-1 tconvs (r -> part2, c -> part2b); paired stats ----
  tconv_quad<2, true><<<dim3(gx(32), 1, 4), TPB, 0, stream>>>(
      r32, 64, nullptr, 0, sc_r32, sh_r32, wb1r, r64, part2, (int)gx(32) * 4, N, 32, 32, 64, 32);
  tconv_quad<4, true><<<dim3(gx(32), 1, 4), TPB, 0, stream>>>(
      c32, 64, s2, 64, sc_c32, sh_c32, wb1c, c64, part2b, (int)gx(32) * 4, N, 64, 64, 128, 32);
  bn_stats2_pair<<<96, TPB, 0, stream>>>(
      part2, g1r, b1r, sc_r64, sh_r64, 32,
      part2b, g1c, b1c, sc_c64, sh_c64, (int)gx(32) * 4, 1.f / (float)(2 * sp64));

  // ---- merged final stride-1 convs -> fp32 outputs ----
  final_two<<<dim3(gx0(64), 1, 2), TPB, 0, stream>>>(
      r64, sc_r64, sh_r64, wbrec, out_rec,
      c64, s1, sc_c64, sh_c64, wbcl, out_cl, N, 64);
}

// Round 18
// 530.448 us; speedup vs baseline: 1.1331x; 1.0087x over previous
//
#include <hip/hip_runtime.h>
#include <hip/hip_bf16.h>

// ---------------------------------------------------------------------------
// UNet3D dense forward, round 18: R17 + tconv_two (level-1 r & c tconvs merged
// into one dispatch; z<4 = r-head CT2, z>=4 = c-head CT4, shared LDS).
// 14 dispatches total.
// ---------------------------------------------------------------------------

using bf16 = __hip_bfloat16;
using ushort4v = __attribute__((ext_vector_type(4))) unsigned short;
using ushort8  = __attribute__((ext_vector_type(8))) unsigned short;
using short8   = __attribute__((ext_vector_type(8))) short;
using f32x4    = __attribute__((ext_vector_type(4))) float;
using float4v  = __attribute__((ext_vector_type(4))) float;

#define TPB 256

static inline int cdiv_l(long a, int b){ return (int)((a + b - 1) / b); }

__device__ __forceinline__ float b2f(unsigned short u){
  union { unsigned int i; float f; } v; v.i = ((unsigned int)u) << 16; return v.f;
}
__device__ __forceinline__ unsigned short f2b(float f){
  union { bf16 h; unsigned short u; } v; v.h = __float2bfloat16(f); return v.u;
}
__device__ __forceinline__ ushort8 bnApply8(ushort8 v, const float* sc, const float* sh, int c){
  float4v s0 = *(const float4v*)(sc + c), s1v = *(const float4v*)(sc + c + 4);
  float4v h0 = *(const float4v*)(sh + c), h1v = *(const float4v*)(sh + c + 4);
  ushort8 r;
#pragma unroll
  for (int j = 0; j < 4; ++j){ float y = b2f(v[j]) * s0[j] + h0[j]; r[j] = f2b(y > 0.f ? y : 0.f); }
#pragma unroll
  for (int j = 0; j < 4; ++j){ float y = b2f(v[j+4]) * s1v[j] + h1v[j]; r[j+4] = f2b(y > 0.f ? y : 0.f); }
  return r;
}

// ---------------- prep: x transpose (blocks 0..2047) + weight repack ----------
__global__ void prep_k(const float* __restrict__ x, unsigned short* __restrict__ xt,
                       const float* __restrict__ w0, const float* __restrict__ w1,
                       const float* __restrict__ w2, const float* __restrict__ wt2r,
                       const float* __restrict__ wt2c, const float* __restrict__ wt1r,
                       const float* __restrict__ wt1c, const float* __restrict__ wt0r,
                       const float* __restrict__ wt0c,
                       unsigned short* __restrict__ wb0p, unsigned short* __restrict__ wb1,
                       unsigned short* __restrict__ wb2, unsigned short* __restrict__ wb2r,
                       unsigned short* __restrict__ wb2c, unsigned short* __restrict__ wb1r,
                       unsigned short* __restrict__ wb1c, unsigned short* __restrict__ wbrec,
                       unsigned short* __restrict__ wbcl){
  __shared__ float l[16][257];
  if (blockIdx.x < 2048) {
    int t = threadIdx.x;
    long p0 = (long)blockIdx.x * 256;
    int n = (int)(p0 >> 18);
    long off = p0 & 262143;
    const float* xb = x + ((long)n * 16) * 262144 + off;
#pragma unroll
    for (int c = 0; c < 16; ++c) l[c][t] = xb[(long)c * 262144 + t];
    __syncthreads();
    ushort8 u0, u1;
#pragma unroll
    for (int k = 0; k < 8; ++k){ u0[k] = f2b(l[k][t]); u1[k] = f2b(l[k + 8][t]); }
    unsigned short* o = xt + (p0 + t) * 16;
    *(ushort8*)o = u0; *(ushort8*)(o + 8) = u1;
    return;
  }
  int idx = (blockIdx.x - 2048) * TPB + threadIdx.x;
  auto enc = [](const float* w, unsigned short* d, int i, int Cin, int Cout){
    int ci = i % Cin; int t = i / Cin; int co = t % Cout; int tap = t / Cout;
    d[i] = f2b(w[((long)co * Cin + ci) * 27 + tap]);
  };
  auto dec = [](const float* w, unsigned short* d, int i, int Cin, int Cout, int CIP, int COP){
    int ci = i % CIP; int t = i / CIP; int co = t % COP; int tap = t / COP;
    float v = (ci < Cin && co < Cout) ? w[((long)tap * Cin + ci) * Cout + co] : 0.f;
    d[i] = f2b(v);
  };
  if (idx < 14336) {
    int i = idx;
    int k = i & 31; int t = i >> 5; int co = t & 31; int pp = t >> 5;
    int tap = pp * 2 + (k >> 4); int ci = k & 15;
    float v = (tap < 27) ? w0[((long)co * 16 + ci) * 27 + tap] : 0.f;
    wb0p[i] = f2b(v);
  }
  else if (idx <   69632) enc(w1,  wb1,  idx - 14336,  32, 64);
  else if (idx <  290816) enc(w2,  wb2,  idx - 69632,  64, 128);
  else if (idx <  512000) dec(wt2r, wb2r, idx - 290816, 128, 64, 128, 64);
  else if (idx <  733184) dec(wt2c, wb2c, idx - 512000, 128, 64, 128, 64);
  else if (idx <  788480) dec(wt1r, wb1r, idx - 733184,  64, 32,  64, 32);
  else if (idx < 1009664) dec(wt1c, wb1c, idx - 788480, 128, 64, 128, 64);
  else if (idx < 1023488) dec(wt0r, wbrec, idx - 1009664, 32, 16,  32, 16);
  else if (idx < 1064960) dec(wt0c, wbcl, idx - 1023488, 96,  2,  96, 16);
}

// ---------------- tconv body (quadrant stride-2, dbuf LDS, fused stats) ----
template <int CO_TILES>
__device__ __forceinline__ void tconv_body(
    unsigned short* xs,              // 2 * 13824 ushorts
    float* redS, float* redQ,        // 4*CO_TILES*4*4 floats (CT<=4 sized)
    const unsigned short* inA, int CA,
    const unsigned short* inB, int CB,
    const float* scA, const float* shA,
    const unsigned short* wb,
    unsigned short* out,
    float* part2, int NB,
    int N, int Cout, int COP, int CIP, int G, int quad) {
  const int tid = threadIdx.x, wv = tid >> 6, l = tid & 63, l15 = l & 15, lg = l >> 4;
  int ntW = G >> 4, ntH = G >> 2, ntD = G >> 2;
  int bx = blockIdx.x;
  const int blkLin = blockIdx.x * 4 + quad;
  int w0 = (bx % ntW) << 4; bx /= ntW;
  int h0 = (bx % ntH) << 2; bx /= ntH;
  int d0 = (bx % ntD) << 2; int n = bx / ntD;
  const int co0 = 0;  // y==1 always here
  const int pd = (quad >> 1) & 1, ph = quad & 1;
  const long spin = (long)G * G * G;

  int nkd, kd_[2], dd_[2], nkh, kh_[2], dh_[2];
  if (pd){ nkd=1; kd_[0]=1; dd_[0]=0; } else { nkd=2; kd_[0]=0; dd_[0]=-1; kd_[1]=2; dd_[1]=0; }
  if (ph){ nkh=1; kh_[0]=1; dh_[0]=0; } else { nkh=2; kh_[0]=0; dh_[0]=-1; kh_[1]=2; dh_[1]=0; }

  f32x4 acc[CO_TILES][4][2];
#pragma unroll
  for (int ct = 0; ct < CO_TILES; ++ct)
#pragma unroll
    for (int j = 0; j < 4; ++j)
#pragma unroll
      for (int p = 0; p < 2; ++p) acc[ct][j][p] = (f32x4){0.f, 0.f, 0.f, 0.f};

  auto stage = [&](int ch, int buf) {
    int c0 = ch << 5;
    const unsigned short* src; int Cs, cl_; bool useBN;
    if (c0 < CA){ src = inA; Cs = CA; cl_ = c0; useBN = (scA != nullptr); }
    else        { src = inB; Cs = CB; cl_ = c0 - CA; useBN = false; }
    const unsigned short* sb = src + (long)n * Cs * spin;
    unsigned short* xb = xs + buf * 13824;
    for (int idx = tid; idx < 4 * 425; idx += TPB) {
      int q = idx / 425, pt = idx - q * 425;
      int zw = pt % 17; int zt = pt / 17; int zh = zt % 5; int zd = zt / 5;
      int gd = d0 + zd - 1, gh = h0 + zh - 1, gw = w0 + zw - 1;
      ushort8 v = (ushort8){0,0,0,0,0,0,0,0};
      if ((unsigned)gd < (unsigned)G && (unsigned)gh < (unsigned)G && (unsigned)gw < (unsigned)G) {
        v = *(const ushort8*)(sb + (((long)gd * G + gh) * G + gw) * Cs + cl_ + q * 8);
        if (useBN) v = bnApply8(v, scA, shA, cl_ + q * 8);
      }
      *(ushort8*)(xb + (q * 432 + pt) * 8) = v;
    }
  };

  const int nch = CIP >> 5;
  stage(0, 0);
  __syncthreads();
#pragma unroll 1
  for (int ch = 0; ch < nch; ++ch) {
    int cur = ch & 1;
    int c0 = ch << 5;
    if (ch + 1 < nch) stage(ch + 1, cur ^ 1);
    const unsigned short* xr = xs + cur * 13824;
#pragma unroll 1
    for (int a = 0; a < nkd; ++a) {
      int zd = wv + 1 + dd_[a];
#pragma unroll 1
      for (int b = 0; b < nkh; ++b) {
        int tapb = (kd_[a] * 3 + kh_[b]) * 3;
        const unsigned short* ap = wb + ((long)tapb * COP + co0 + l15) * CIP + c0 + lg * 8;
        long tstride = (long)COP * CIP;
        short8 Ak0[CO_TILES], Ak1[CO_TILES], Ak2[CO_TILES];
#pragma unroll
        for (int ct = 0; ct < CO_TILES; ++ct) {
          Ak0[ct] = *(const short8*)(ap + ct * 16 * CIP);
          Ak1[ct] = *(const short8*)(ap + tstride + ct * 16 * CIP);
          Ak2[ct] = *(const short8*)(ap + 2 * tstride + ct * 16 * CIP);
        }
        int zh0 = 1 + dh_[b];
#pragma unroll
        for (int j = 0; j < 4; ++j) {
          int basept = (zd * 5 + (j + zh0)) * 17 + l15;
          short8 Bm = *(const short8*)(xr + (lg * 432 + basept) * 8);
          short8 B0 = *(const short8*)(xr + (lg * 432 + basept + 1) * 8);
#pragma unroll
          for (int ct = 0; ct < CO_TILES; ++ct) {
            acc[ct][j][0] = __builtin_amdgcn_mfma_f32_16x16x32_bf16(Ak0[ct], Bm, acc[ct][j][0], 0, 0, 0);
            acc[ct][j][0] = __builtin_amdgcn_mfma_f32_16x16x32_bf16(Ak2[ct], B0, acc[ct][j][0], 0, 0, 0);
            acc[ct][j][1] = __builtin_amdgcn_mfma_f32_16x16x32_bf16(Ak1[ct], B0, acc[ct][j][1], 0, 0, 0);
          }
        }
      }
    }
    __syncthreads();
  }

  int Gout = 2 * G; long spo = (long)Gout * Gout * Gout;
  int od = 2 * (d0 + wv) + pd;
#pragma unroll
  for (int j = 0; j < 4; ++j) {
    int oh = 2 * (h0 + j) + ph;
#pragma unroll
    for (int p = 0; p < 2; ++p) {
      int ow = 2 * (w0 + l15) + p;
      long pt = ((long)od * Gout + oh) * Gout + ow;
#pragma unroll
      for (int ct = 0; ct < CO_TILES; ++ct) {
        ushort4v pk;
#pragma unroll
        for (int r = 0; r < 4; ++r) pk[r] = f2b(acc[ct][j][p][r]);
        *(ushort4v*)(out + ((long)n * spo + pt) * Cout + co0 + ct * 16 + lg * 4) = pk;
      }
    }
  }

  // stats
#pragma unroll
  for (int ct = 0; ct < CO_TILES; ++ct)
#pragma unroll
    for (int r = 0; r < 4; ++r) {
      float s = 0.f, q = 0.f;
#pragma unroll
      for (int j = 0; j < 4; ++j)
#pragma unroll
        for (int p = 0; p < 2; ++p) { float a = acc[ct][j][p][r]; s += a; q += a * a; }
#pragma unroll
      for (int m = 1; m < 16; m <<= 1) { s += __shfl_xor(s, m); q += __shfl_xor(q, m); }
      if (l15 == 0) {
        int ix = ((wv * CO_TILES + ct) * 4 + lg) * 4 + r;
        redS[ix] = s; redQ[ix] = q;
      }
    }
  __syncthreads();
  if (tid < CO_TILES * 16) {
    int ct = tid >> 4, lg2 = (tid >> 2) & 3, r = tid & 3;
    float s = 0.f, q = 0.f;
#pragma unroll
    for (int w2 = 0; w2 < 4; ++w2) {
      int ix = ((w2 * CO_TILES + ct) * 4 + lg2) * 4 + r;
      s += redS[ix]; q += redQ[ix];
    }
    int c = co0 + ct * 16 + lg2 * 4 + r;
    long slot = (long)c * NB + blkLin;
    part2[slot * 2] = s; part2[slot * 2 + 1] = q;
  }
}

// ---------------- merged level-1 tconvs: z<4 r-head CT2, z>=4 c-head CT4 ---
__global__ __launch_bounds__(TPB, 2) void tconv_two(
    const unsigned short* __restrict__ r32,
    const float* __restrict__ sc_r32, const float* __restrict__ sh_r32,
    const unsigned short* __restrict__ wb1r, unsigned short* __restrict__ r64,
    float* __restrict__ part2,
    const unsigned short* __restrict__ c32, const unsigned short* __restrict__ s2,
    const float* __restrict__ sc_c32, const float* __restrict__ sh_c32,
    const unsigned short* __restrict__ wb1c, unsigned short* __restrict__ c64,
    float* __restrict__ part2b,
    int NB, int N, int G) {
  __shared__ unsigned short xs[2 * 13824];
  __shared__ float redS[4 * 4 * 4 * 4];
  __shared__ float redQ[4 * 4 * 4 * 4];
  int z = blockIdx.z;
  if (z < 4) {
    tconv_body<2>(xs, redS, redQ, r32, 64, nullptr, 0, sc_r32, sh_r32,
                  wb1r, r64, part2, NB, N, 32, 32, 64, G, z);
  } else {
    tconv_body<4>(xs, redS, redQ, c32, 64, s2, 64, sc_c32, sh_c32,
                  wb1c, c64, part2b, NB, N, 64, 64, 128, G, z - 4);
  }
}

// ---------------- dual-head quadrant tconv2 (shared s4 staging) ------------
__global__ __launch_bounds__(TPB) void tconv_dual(
    const unsigned short* __restrict__ in, int CI,
    const float* __restrict__ scA, const float* __restrict__ shA,
    const unsigned short* __restrict__ wbA, const unsigned short* __restrict__ wbB,
    unsigned short* __restrict__ outA, unsigned short* __restrict__ outB,
    float* __restrict__ p2A, float* __restrict__ p2B, int NB,
    int N, int Cout, int COP, int CIP, int G) {
  const int CT = 2;
  __shared__ unsigned short xs[4 * 432 * 8];
  const int tid = threadIdx.x, wv = tid >> 6, l = tid & 63, l15 = l & 15, lg = l >> 4;
  int ntW = G >> 4, ntH = G >> 2, ntD = G >> 2;
  int bx = blockIdx.x;
  const int blkLin = blockIdx.x * 4 + blockIdx.z;
  int w0 = (bx % ntW) << 4; bx /= ntW;
  int h0 = (bx % ntH) << 2; bx /= ntH;
  int d0 = (bx % ntD) << 2; int n = bx / ntD;
  const int co0 = blockIdx.y * (16 * CT);
  const int quad = blockIdx.z;
  const int pd = (quad >> 1) & 1, ph = quad & 1;
  const long spin = (long)G * G * G;

  int nkd, kd_[2], dd_[2], nkh, kh_[2], dh_[2];
  if (pd){ nkd=1; kd_[0]=1; dd_[0]=0; } else { nkd=2; kd_[0]=0; dd_[0]=-1; kd_[1]=2; dd_[1]=0; }
  if (ph){ nkh=1; kh_[0]=1; dh_[0]=0; } else { nkh=2; kh_[0]=0; dh_[0]=-1; kh_[1]=2; dh_[1]=0; }

  f32x4 acc[2][CT][4][2];
#pragma unroll
  for (int h = 0; h < 2; ++h)
#pragma unroll
    for (int ct = 0; ct < CT; ++ct)
#pragma unroll
      for (int j = 0; j < 4; ++j)
#pragma unroll
        for (int p = 0; p < 2; ++p) acc[h][ct][j][p] = (f32x4){0.f, 0.f, 0.f, 0.f};

  const int nch = CIP >> 5;
#pragma unroll 1
  for (int ch = 0; ch < nch; ++ch) {
    int c0 = ch << 5;
    const unsigned short* sb = in + (long)n * CI * spin;
    __syncthreads();
    for (int idx = tid; idx < 4 * 425; idx += TPB) {
      int q = idx / 425, pt = idx - q * 425;
      int zw = pt % 17; int zt = pt / 17; int zh = zt % 5; int zd = zt / 5;
      int gd = d0 + zd - 1, gh = h0 + zh - 1, gw = w0 + zw - 1;
      ushort8 v = (ushort8){0,0,0,0,0,0,0,0};
      if ((unsigned)gd < (unsigned)G && (unsigned)gh < (unsigned)G && (unsigned)gw < (unsigned)G) {
        v = *(const ushort8*)(sb + (((long)gd * G + gh) * G + gw) * CI + c0 + q * 8);
        v = bnApply8(v, scA, shA, c0 + q * 8);
      }
      *(ushort8*)(xs + (q * 432 + pt) * 8) = v;
    }
    __syncthreads();
#pragma unroll 1
    for (int a = 0; a < nkd; ++a) {
      int zd = wv + 1 + dd_[a];
#pragma unroll 1
      for (int b = 0; b < nkh; ++b) {
        int tapb = (kd_[a] * 3 + kh_[b]) * 3;
        long tstride = (long)COP * CIP;
        long abase = ((long)tapb * COP + co0 + l15) * CIP + c0 + lg * 8;
        int zh0 = 1 + dh_[b];
#pragma unroll
        for (int h = 0; h < 2; ++h) {
          const unsigned short* ap = (h == 0 ? wbA : wbB) + abase;
          short8 Ak0[CT], Ak1[CT], Ak2[CT];
#pragma unroll
          for (int ct = 0; ct < CT; ++ct) {
            Ak0[ct] = *(const short8*)(ap + ct * 16 * CIP);
            Ak1[ct] = *(const short8*)(ap + tstride + ct * 16 * CIP);
            Ak2[ct] = *(const short8*)(ap + 2 * tstride + ct * 16 * CIP);
          }
#pragma unroll
          for (int j = 0; j < 4; ++j) {
            int basept = (zd * 5 + (j + zh0)) * 17 + l15;
            short8 Bm = *(const short8*)(xs + (lg * 432 + basept) * 8);
            short8 B0 = *(const short8*)(xs + (lg * 432 + basept + 1) * 8);
#pragma unroll
            for (int ct = 0; ct < CT; ++ct) {
              acc[h][ct][j][0] = __builtin_amdgcn_mfma_f32_16x16x32_bf16(Ak0[ct], Bm, acc[h][ct][j][0], 0, 0, 0);
              acc[h][ct][j][0] = __builtin_amdgcn_mfma_f32_16x16x32_bf16(Ak2[ct], B0, acc[h][ct][j][0], 0, 0, 0);
              acc[h][ct][j][1] = __builtin_amdgcn_mfma_f32_16x16x32_bf16(Ak1[ct], B0, acc[h][ct][j][1], 0, 0, 0);
            }
          }
        }
      }
    }
  }

  int Gout = 2 * G; long spo = (long)Gout * Gout * Gout;
  int od = 2 * (d0 + wv) + pd;
#pragma unroll
  for (int j = 0; j < 4; ++j) {
    int oh = 2 * (h0 + j) + ph;
#pragma unroll
    for (int p = 0; p < 2; ++p) {
      int ow = 2 * (w0 + l15) + p;
      long pt = ((long)od * Gout + oh) * Gout + ow;
#pragma unroll
      for (int h = 0; h < 2; ++h) {
        unsigned short* o = h == 0 ? outA : outB;
#pragma unroll
        for (int ct = 0; ct < CT; ++ct) {
          ushort4v pk;
#pragma unroll
          for (int r = 0; r < 4; ++r) pk[r] = f2b(acc[h][ct][j][p][r]);
          *(ushort4v*)(o + ((long)n * spo + pt) * Cout + co0 + ct * 16 + lg * 4) = pk;
        }
      }
    }
  }

  __shared__ float redS[4][CT][4][4];
  __shared__ float redQ[4][CT][4][4];
#pragma unroll 1
  for (int h = 0; h < 2; ++h) {
    __syncthreads();
#pragma unroll
    for (int ct = 0; ct < CT; ++ct)
#pragma unroll
      for (int r = 0; r < 4; ++r) {
        float s = 0.f, q = 0.f;
#pragma unroll
        for (int j = 0; j < 4; ++j)
#pragma unroll
          for (int p = 0; p < 2; ++p) { float a = acc[h][ct][j][p][r]; s += a; q += a * a; }
#pragma unroll
        for (int m = 1; m < 16; m <<= 1) { s += __shfl_xor(s, m); q += __shfl_xor(q, m); }
        if (l15 == 0) { redS[wv][ct][lg][r] = s; redQ[wv][ct][lg][r] = q; }
      }
    __syncthreads();
    if (tid < CT * 16) {
      int ct = tid >> 4, lg2 = (tid >> 2) & 3, r = tid & 3;
      float s = 0.f, q = 0.f;
#pragma unroll
      for (int w2 = 0; w2 < 4; ++w2) { s += redS[w2][ct][lg2][r]; q += redQ[w2][ct][lg2][r]; }
      int c = co0 + ct * 16 + lg2 * 4 + r;
      long slot = (long)c * NB + blkLin;
      float* p2 = h == 0 ? p2A : p2B;
      p2[slot * 2] = s; p2[slot * 2 + 1] = q;
    }
  }
}

// ---------------- unified NDHWC MFMA conv (PAIRED conv0 / V2 stride-2) -----
template <int VARIANT, int CO_TILES, bool PAIRED, bool FOUT, bool STATS>
__global__ __launch_bounds__(TPB) void mconv(
    const unsigned short* __restrict__ inA, int CA,
    const unsigned short* __restrict__ inB, int CB,
    const float* __restrict__ scA, const float* __restrict__ shA,
    const unsigned short* __restrict__ wb,
    void* __restrict__ outv,
    float* __restrict__ part2, int NB,
    int N, int Cout, int COP, int CIP, int G) {
  const int tid = threadIdx.x, wv = tid >> 6, l = tid & 63, l15 = l & 15, lg = l >> 4;
  int bx = blockIdx.x;
  const int blkLin = blockIdx.x;
  int w0, h0, d0, n;
  int wvd = wv & 1, jh = wv >> 1, jbase = jh * 4;
  if constexpr (VARIANT == 0) {
    int ntW = G >> 4, ntH = G >> 3, ntD = G >> 1;
    w0 = (bx % ntW) << 4; bx /= ntW;
    h0 = (bx % ntH) << 3; bx /= ntH;
    d0 = (bx % ntD) << 1; n = bx / ntD;
  } else {
    int ntW = G >> 4, ntH = G >> 2, ntD = G >> 2;
    w0 = (bx % ntW) << 4; bx /= ntW;
    h0 = (bx % ntH) << 2; bx /= ntH;
    d0 = (bx % ntD) << 2; n = bx / ntD;
  }
  const int co0 = blockIdx.y * (16 * CO_TILES);
  const int Gin = (VARIANT == 2) ? 2 * G : G;
  const long spin = (long)Gin * Gin * Gin;

  f32x4 acc[CO_TILES][4];
#pragma unroll
  for (int ct = 0; ct < CO_TILES; ++ct)
#pragma unroll
    for (int j = 0; j < 4; ++j) acc[ct][j] = (f32x4){0.f, 0.f, 0.f, 0.f};

  if constexpr (PAIRED) {
    __shared__ unsigned short xs[2 * 728 * 8];
    const unsigned short* src = inA + (long)n * 16 * spin;
    for (int idx = tid; idx < 2 * 720; idx += TPB) {
      int q = idx / 720, pt = idx - q * 720;
      int zw = pt % 18; int zt = pt / 18; int zh = zt % 10; int zd = zt / 10;
      int gd = d0 + zd - 1, gh = h0 + zh - 1, gw = w0 + zw - 1;
      ushort8 v = (ushort8){0,0,0,0,0,0,0,0};
      if ((unsigned)gd < (unsigned)G && (unsigned)gh < (unsigned)G && (unsigned)gw < (unsigned)G)
        v = *(const ushort8*)(src + (((long)gd * G + gh) * G + gw) * 16 + q * 8);
      *(ushort8*)(xs + (q * 728 + pt) * 8) = v;
    }
    __syncthreads();
#pragma unroll 1
    for (int pp = 0; pp < 14; ++pp) {
      short8 A0 = *(const short8*)(wb + ((pp * 32 + l15) * 32) + lg * 8);
      short8 A1 = *(const short8*)(wb + ((pp * 32 + 16 + l15) * 32) + lg * 8);
      int t0 = 2 * pp + (lg >> 1); if (t0 > 26) t0 = 26;
      int dd = t0 / 9 - 1, dh = (t0 / 3) % 3 - 1, dw = t0 % 3 - 1;
      int q = lg & 1;
      int zd = wvd + 1 + dd;
      int base = (q * 728 + (zd * 10 + (1 + dh + jbase)) * 18 + 1 + l15 + dw) * 8;
#pragma unroll
      for (int j = 0; j < 4; ++j) {
        short8 B = *(const short8*)(xs + base + j * (18 * 8));
        acc[0][j] = __builtin_amdgcn_mfma_f32_16x16x32_bf16(A0, B, acc[0][j], 0, 0, 0);
        if (CO_TILES == 2)
          acc[1][j] = __builtin_amdgcn_mfma_f32_16x16x32_bf16(A1, B, acc[1][j], 0, 0, 0);
      }
    }
  } else {
    const int nch = CIP >> 5;
#pragma unroll 1
    for (int ch = 0; ch < nch; ++ch) {
      int c0 = ch << 5;
      const unsigned short* src; int Cs, cl_;
      if (c0 < CA){ src = inA; Cs = CA; cl_ = c0; } else { src = inB; Cs = CB; cl_ = c0 - CA; }
      const unsigned short* sb = src + (long)n * Cs * spin;
#pragma unroll 1
      for (int a = 0; a < 3; ++a) {
        int gd = 2 * (d0 + wv) + a - 1;
        bool vd = (unsigned)gd < (unsigned)Gin;
#pragma unroll 1
        for (int b = 0; b < 3; ++b) {
#pragma unroll
          for (int c = 0; c < 3; ++c) {
            int tap = (a * 3 + b) * 3 + c;
            const unsigned short* ap = wb + ((long)tap * COP + co0 + l15) * CIP + c0 + lg * 8;
            short8 A0 = *(const short8*)ap;
            short8 A1;
            if (CO_TILES == 2) A1 = *(const short8*)(ap + 16 * CIP);
            int gw = 2 * (w0 + l15) + c - 1;
            bool vdw = vd && ((unsigned)gw < (unsigned)Gin);
#pragma unroll
            for (int j = 0; j < 4; ++j) {
              int gh = 2 * (h0 + j) + b - 1;
              short8 B = (short8){0,0,0,0,0,0,0,0};
              if (vdw && (unsigned)gh < (unsigned)Gin)
                B = *(const short8*)(sb + (((long)gd * Gin + gh) * Gin + gw) * Cs + cl_ + lg * 8);
              acc[0][j] = __builtin_amdgcn_mfma_f32_16x16x32_bf16(A0, B, acc[0][j], 0, 0, 0);
              if (CO_TILES == 2)
                acc[1][j] = __builtin_amdgcn_mfma_f32_16x16x32_bf16(A1, B, acc[1][j], 0, 0, 0);
            }
          }
        }
      }
    }
  }

  const long spo = (long)G * G * G;
#pragma unroll
  for (int j = 0; j < 4; ++j) {
    long pt;
    if constexpr (VARIANT == 0)
      pt = ((long)(d0 + wvd) * G + (h0 + jbase + j)) * G + (w0 + l15);
    else
      pt = ((long)(d0 + wv) * G + (h0 + j)) * G + (w0 + l15);
    if constexpr (!FOUT) {
      unsigned short* outp = (unsigned short*)outv;
#pragma unroll
      for (int ct = 0; ct < CO_TILES; ++ct) {
        ushort4v pk;
#pragma unroll
        for (int r = 0; r < 4; ++r) pk[r] = f2b(acc[ct][j][r]);
        *(ushort4v*)(outp + ((long)n * spo + pt) * Cout + co0 + ct * 16 + lg * 4) = pk;
      }
    } else {
      float* outp = (float*)outv;
#pragma unroll
      for (int ct = 0; ct < CO_TILES; ++ct)
#pragma unroll
        for (int r = 0; r < 4; ++r) {
          int co = co0 + ct * 16 + lg * 4 + r;
          if (co < Cout) outp[((long)(n * Cout + co)) * spo + pt] = acc[ct][j][r];
        }
    }
  }

  if constexpr (STATS) {
    __shared__ float redS[4][CO_TILES][4][4];
    __shared__ float redQ[4][CO_TILES][4][4];
#pragma unroll
    for (int ct = 0; ct < CO_TILES; ++ct)
#pragma unroll
      for (int r = 0; r < 4; ++r) {
        float s = 0.f, q = 0.f;
#pragma unroll
        for (int j = 0; j < 4; ++j) { float a = acc[ct][j][r]; s += a; q += a * a; }
#pragma unroll
        for (int m = 1; m < 16; m <<= 1) { s += __shfl_xor(s, m); q += __shfl_xor(q, m); }
        if (l15 == 0) { redS[wv][ct][lg][r] = s; redQ[wv][ct][lg][r] = q; }
      }
    __syncthreads();
    if (tid < CO_TILES * 16) {
      int ct = tid >> 4, lg2 = (tid >> 2) & 3, r = tid & 3;
      float s = 0.f, q = 0.f;
#pragma unroll
      for (int w2 = 0; w2 < 4; ++w2) { s += redS[w2][ct][lg2][r]; q += redQ[w2][ct][lg2][r]; }
      int c = co0 + ct * 16 + lg2 * 4 + r;
      long slot = (long)c * NB + blkLin;
      part2[slot * 2] = s; part2[slot * 2 + 1] = q;
    }
  }
}

// ---------------- merged final stride-1 convs: z=0 rec, z=1 cl -------------
__global__ __launch_bounds__(TPB) void final_two(
    const unsigned short* __restrict__ r64,
    const float* __restrict__ sc_r64, const float* __restrict__ sh_r64,
    const unsigned short* __restrict__ wbrec, float* __restrict__ out_rec,
    const unsigned short* __restrict__ c64, const unsigned short* __restrict__ s1,
    const float* __restrict__ sc_c64, const float* __restrict__ sh_c64,
    const unsigned short* __restrict__ wbcl, float* __restrict__ out_cl,
    int N, int G) {
  const unsigned short* inA; int CA; const unsigned short* inB; int CB;
  const float* scA; const float* shA; const unsigned short* wb;
  float* outp; int Cout, COP, CIP;
  if (blockIdx.z == 0) {
    inA = r64; CA = 32; inB = nullptr; CB = 0; scA = sc_r64; shA = sh_r64;
    wb = wbrec; outp = out_rec; Cout = 16; COP = 16; CIP = 32;
  } else {
    inA = c64; CA = 64; inB = s1; CB = 32; scA = sc_c64; shA = sh_c64;
    wb = wbcl; outp = out_cl; Cout = 2; COP = 16; CIP = 96;
  }
  const int tid = threadIdx.x, wv = tid >> 6, l = tid & 63, l15 = l & 15, lg = l >> 4;
  int bx = blockIdx.x;
  int wvd = wv & 1, jh = wv >> 1, jbase = jh * 4;
  int ntW = G >> 4, ntH = G >> 3, ntD = G >> 1;
  int w0 = (bx % ntW) << 4; bx /= ntW;
  int h0 = (bx % ntH) << 3; bx /= ntH;
  int d0 = (bx % ntD) << 1; int n = bx / ntD;
  const long spin = (long)G * G * G;

  f32x4 acc[4];
#pragma unroll
  for (int j = 0; j < 4; ++j) acc[j] = (f32x4){0.f, 0.f, 0.f, 0.f};

  __shared__ unsigned short xs[4 * 728 * 8];
  const int nch = CIP >> 5;
#pragma unroll 1
  for (int ch = 0; ch < nch; ++ch) {
    int c0 = ch << 5;
    const unsigned short* src; int Cs, cl_; bool useBN;
    if (c0 < CA){ src = inA; Cs = CA; cl_ = c0; useBN = (scA != nullptr); }
    else        { src = inB; Cs = CB; cl_ = c0 - CA; useBN = false; }
    const unsigned short* sb = src + (long)n * Cs * spin;
    __syncthreads();
    for (int idx = tid; idx < 4 * 720; idx += TPB) {
      int q = idx / 720, pt = idx - q * 720;
      int zw = pt % 18; int zt = pt / 18; int zh = zt % 10; int zd = zt / 10;
      int gd = d0 + zd - 1, gh = h0 + zh - 1, gw = w0 + zw - 1;
      ushort8 v = (ushort8){0,0,0,0,0,0,0,0};
      if ((unsigned)gd < (unsigned)G && (unsigned)gh < (unsigned)G && (unsigned)gw < (unsigned)G) {
        v = *(const ushort8*)(sb + (((long)gd * G + gh) * G + gw) * Cs + cl_ + q * 8);
        if (useBN) v = bnApply8(v, scA, shA, cl_ + q * 8);
      }
      *(ushort8*)(xs + (q * 728 + pt) * 8) = v;
    }
    __syncthreads();
#pragma unroll 1
    for (int a = 0; a < 3; ++a) {
      int zd = wvd + a;
      short8 A0[3][3];
#pragma unroll
      for (int b = 0; b < 3; ++b)
#pragma unroll
        for (int c = 0; c < 3; ++c) {
          int tap = (a * 3 + b) * 3 + c;
          A0[b][c] = *(const short8*)(wb + ((long)tap * COP + l15) * CIP + c0 + lg * 8);
        }
#pragma unroll
      for (int sl = 0; sl < 6; ++sl) {
        int sg = jbase + sl;
        int rb = (lg * 728 + (zd * 10 + sg) * 18 + l15) * 8;
        short8 B0 = *(const short8*)(xs + rb);
        short8 B1 = *(const short8*)(xs + rb + 8);
        short8 B2 = *(const short8*)(xs + rb + 16);
#pragma unroll
        for (int b = 0; b < 3; ++b) {
          int j = sl - b;
          if (j >= 0 && j < 4) {
            acc[j] = __builtin_amdgcn_mfma_f32_16x16x32_bf16(A0[b][0], B0, acc[j], 0, 0, 0);
            acc[j] = __builtin_amdgcn_mfma_f32_16x16x32_bf16(A0[b][1], B1, acc[j], 0, 0, 0);
            acc[j] = __builtin_amdgcn_mfma_f32_16x16x32_bf16(A0[b][2], B2, acc[j], 0, 0, 0);
          }
        }
      }
    }
  }

  const long spo = (long)G * G * G;
#pragma unroll
  for (int j = 0; j < 4; ++j) {
    long pt = ((long)(d0 + wvd) * G + (h0 + jbase + j)) * G + (w0 + l15);
#pragma unroll
    for (int r = 0; r < 4; ++r) {
      int co = lg * 4 + r;
      if (co < Cout) outp[((long)(n * Cout + co)) * spo + pt] = acc[j][r];
    }
  }
}

// ---------------- stats reduce: single ----------------
__global__ void bn_stats2b(const float* __restrict__ part2, const float* __restrict__ g,
                           const float* __restrict__ b, float* __restrict__ sc,
                           float* __restrict__ sh, int NB, float inv_cnt){
  int c = blockIdx.x, tid = threadIdx.x;
  float s = 0.f, q = 0.f;
  for (int i = tid; i < NB; i += TPB) {
    s += part2[((long)c * NB + i) * 2];
    q += part2[((long)c * NB + i) * 2 + 1];
  }
  __shared__ float ss[TPB], qq[TPB];
  ss[tid] = s; qq[tid] = q;
  __syncthreads();
  for (int off = TPB / 2; off > 0; off >>= 1) {
    if (tid < off) { ss[tid] += ss[tid + off]; qq[tid] += qq[tid + off]; }
    __syncthreads();
  }
  if (tid == 0) {
    float m = ss[0] * inv_cnt, v = qq[0] * inv_cnt - m * m;
    float rs = rsqrtf(v + 1e-5f) * g[c];
    sc[c] = rs;
    sh[c] = b[c] - m * rs;
  }
}

// ---------------- stats reduce: paired ----------------
__global__ void bn_stats2_pair(
    const float* __restrict__ pA, const float* __restrict__ gA, const float* __restrict__ bA,
    float* __restrict__ scA, float* __restrict__ shA, int CAch,
    const float* __restrict__ pB, const float* __restrict__ gB, const float* __restrict__ bB,
    float* __restrict__ scB, float* __restrict__ shB,
    int NB, float inv_cnt){
  int c = blockIdx.x, tid = threadIdx.x;
  const float* part; const float* g; const float* b; float* sc; float* sh; int cc;
  if (c < CAch) { part = pA; g = gA; b = bA; sc = scA; sh = shA; cc = c; }
  else          { part = pB; g = gB; b = bB; sc = scB; sh = shB; cc = c - CAch; }
  float s = 0.f, q = 0.f;
  for (int i = tid; i < NB; i += TPB) {
    s += part[((long)cc * NB + i) * 2];
    q += part[((long)cc * NB + i) * 2 + 1];
  }
  __shared__ float ss[TPB], qq[TPB];
  ss[tid] = s; qq[tid] = q;
  __syncthreads();
  for (int off = TPB / 2; off > 0; off >>= 1) {
    if (tid < off) { ss[tid] += ss[tid + off]; qq[tid] += qq[tid + off]; }
    __syncthreads();
  }
  if (tid == 0) {
    float m = ss[0] * inv_cnt, v = qq[0] * inv_cnt - m * m;
    float rs = rsqrtf(v + 1e-5f) * g[cc];
    sc[cc] = rs;
    sh[cc] = b[cc] - m * rs;
  }
}

// ---------------- BN apply + ReLU pass (for s1, s2 only) ----------------
__global__ void bn_relu_cl(unsigned short* __restrict__ x, const float* __restrict__ sc,
                           const float* __restrict__ sh, int C, long tot8){
  long i8 = (long)blockIdx.x * TPB + threadIdx.x;
  if (i8 >= tot8) return;
  long e = i8 * 8;
  int c0 = (int)(e & (C - 1));
  ushort8 v = *(ushort8*)(x + e);
  *(ushort8*)(x + e) = bnApply8(v, sc, sh, c0);
}

extern "C" void kernel_launch(void* const* d_in, const int* in_sizes, int n_in,
                              void* d_out, int out_size, void* d_ws, size_t ws_size,
                              hipStream_t stream) {
  const float* x    = (const float*)d_in[0];
  const float* w0   = (const float*)d_in[1];
  const float* g0   = (const float*)d_in[2];
  const float* b0   = (const float*)d_in[3];
  const float* w1   = (const float*)d_in[4];
  const float* g1   = (const float*)d_in[5];
  const float* b1   = (const float*)d_in[6];
  const float* w2   = (const float*)d_in[7];
  const float* g2   = (const float*)d_in[8];
  const float* b2   = (const float*)d_in[9];
  const float* wt2r = (const float*)d_in[10];
  const float* g2r  = (const float*)d_in[11];
  const float* b2r  = (const float*)d_in[12];
  const float* wt1r = (const float*)d_in[13];
  const float* g1r  = (const float*)d_in[14];
  const float* b1r  = (const float*)d_in[15];
  const float* wt0r = (const float*)d_in[16];
  const float* wt2c = (const float*)d_in[17];
  const float* g2c  = (const float*)d_in[18];
  const float* b2c  = (const float*)d_in[19];
  const float* wt1c = (const float*)d_in[20];
  const float* g1c  = (const float*)d_in[21];
  const float* b1c  = (const float*)d_in[22];
  const float* wt0c = (const float*)d_in[23];

  const int N = 2;
  const long sp64 = 262144, sp32 = 32768, sp16 = 4096;

  // ---- workspace (ushort units), all activations NDHWC bf16 ----
  unsigned short* W = (unsigned short*)d_ws;
  unsigned short* s1   = W;                       // [2*sp64][32]
  unsigned short* s2   = s1  + 16777216;          // [2*sp32][64]
  unsigned short* s4   = s2  + 4194304;           // [2*sp16][128]
  unsigned short* r32  = s4  + 1048576;           // [2*sp32][64]
  unsigned short* c32  = r32 + 4194304;           // [2*sp32][64]
  unsigned short* r64  = c32 + 4194304;           // [2*sp64][32]
  unsigned short* xt   = r64;                     // alias (dead after conv0)
  unsigned short* c64  = r64 + 16777216;          // [2*sp64][64]
  unsigned short* wb0p = c64 + 33554432;          // 14*32*32
  unsigned short* wb1  = wb0p + 14336;            // 27*64*32
  unsigned short* wb2  = wb1  + 55296;            // 27*128*64
  unsigned short* wb2r = wb2  + 221184;           // 27*64*128
  unsigned short* wb2c = wb2r + 221184;
  unsigned short* wb1r = wb2c + 221184;           // 27*32*64
  unsigned short* wb1c = wb1r + 55296;            // 27*64*128
  unsigned short* wbrec= wb1c + 221184;           // 27*16*32
  unsigned short* wbcl = wbrec+ 13824;            // 27*16*96
  float* part2  = (float*)(wbcl + 41472);         // 131072 f32
  float* part2b = part2 + 131072;                 // 131072 f32
  float* bsc  = part2b + 131072;                  // shared (s1, s2)
  float* bsh  = bsc + 128;
  float* sc_s4  = bsh  + 128; float* sh_s4  = sc_s4  + 128;
  float* sc_r32 = sh_s4 + 128; float* sh_r32 = sc_r32 + 128;
  float* sc_c32 = sh_r32+ 128; float* sh_c32 = sc_c32 + 128;
  float* sc_r64 = sh_c32+ 128; float* sh_r64 = sc_r64 + 128;
  float* sc_c64 = sh_r64+ 128; float* sh_c64 = sc_c64 + 128;

  float* out_cl  = (float*)d_out;                 // [2][2][64^3] NCDHW
  float* out_rec = (float*)d_out + 2L * 2 * sp64; // [2][16][64^3]

  // ---- prep: weight repack + x transpose (one dispatch) ----
  prep_k<<<2048 + cdiv_l(1064960, TPB), TPB, 0, stream>>>(
      x, xt, w0, w1, w2, wt2r, wt2c, wt1r, wt1c, wt0r, wt0c,
      wb0p, wb1, wb2, wb2r, wb2c, wb1r, wb1c, wbrec, wbcl);

  auto gx0 = [&](int G){ return (unsigned)(N * (G >> 1) * (G >> 3) * (G >> 4)); };
  auto gx  = [&](int G){ return (unsigned)(N * (G >> 2) * (G >> 2) * (G >> 4)); };

  // ---- encoder ----
  mconv<0, 2, true, false, true><<<dim3(gx0(64), 1), TPB, 0, stream>>>(
      xt, 16, nullptr, 0, nullptr, nullptr, wb0p, s1, part2, (int)gx0(64), N, 32, 32, 32, 64);
  bn_stats2b<<<32, TPB, 0, stream>>>(part2, g0, b0, bsc, bsh, (int)gx0(64), 1.f / (float)(2 * sp64));
  bn_relu_cl<<<cdiv_l(2 * sp64 * 32 / 8, TPB), TPB, 0, stream>>>(s1, bsc, bsh, 32, 2 * sp64 * 32 / 8);

  mconv<2, 2, false, false, true><<<dim3(gx(32), 2), TPB, 0, stream>>>(
      s1, 32, nullptr, 0, nullptr, nullptr, wb1, s2, part2, (int)gx(32), N, 64, 64, 32, 32);
  bn_stats2b<<<64, TPB, 0, stream>>>(part2, g1, b1, bsc, bsh, (int)gx(32), 1.f / (float)(2 * sp32));
  bn_relu_cl<<<cdiv_l(2 * sp32 * 64 / 8, TPB), TPB, 0, stream>>>(s2, bsc, bsh, 64, 2 * sp32 * 64 / 8);

  mconv<2, 1, false, false, true><<<dim3(gx(16), 8), TPB, 0, stream>>>(
      s2, 64, nullptr, 0, nullptr, nullptr, wb2, s4, part2, (int)gx(16), N, 128, 128, 64, 16);
  bn_stats2b<<<128, TPB, 0, stream>>>(part2, g2, b2, sc_s4, sh_s4, (int)gx(16), 1.f / (float)(2 * sp16));

  // ---- level-2 dual tconv (s4 staged once) -> r32, c32; paired stats ----
  tconv_dual<<<dim3(gx(16), 2, 4), TPB, 0, stream>>>(
      s4, 128, sc_s4, sh_s4, wb2r, wb2c, r32, c32, part2, part2b, (int)gx(16) * 4,
      N, 64, 64, 128, 16);
  bn_stats2_pair<<<128, TPB, 0, stream>>>(
      part2, g2r, b2r, sc_r32, sh_r32, 64,
      part2b, g2c, b2c, sc_c32, sh_c32, (int)gx(16) * 4, 1.f / (float)(2 * sp32));

  // ---- level-1 tconvs merged (r & c heads in one dispatch); paired stats ----
  tconv_two<<<dim3(gx(32), 1, 8), TPB, 0, stream>>>(
      r32, sc_r32, sh_r32, wb1r, r64, part2,
      c32, s2, sc_c32, sh_c32, wb1c, c64, part2b,
      (int)gx(32) * 4, N, 32);
  bn_stats2_pair<<<96, TPB, 0, stream>>>(
      part2, g1r, b1r, sc_r64, sh_r64, 32,
      part2b, g1c, b1c, sc_c64, sh_c64, (int)gx(32) * 4, 1.f / (float)(2 * sp64));

  // ---- merged final stride-1 convs -> fp32 outputs ----
  final_two<<<dim3(gx0(64), 1, 2), TPB, 0, stream>>>(
      r64, sc_r64, sh_r64, wbrec, out_rec,
      c64, s1, sc_c64, sh_c64, wbcl, out_cl, N, 64);
}